// Round 2
// baseline (4865.746 us; speedup 1.0000x reference)
//
#include <hip/hip_runtime.h>

typedef unsigned short u16;
typedef unsigned int u32;
typedef __bf16 bf16x8 __attribute__((ext_vector_type(8)));
typedef float f32x4 __attribute__((ext_vector_type(4)));

#define ND 512
#define DWR 300
#define DWP 320
#define DSR 16
#define DSP 32
#define NCLS 13

__device__ __forceinline__ float bf2f(u16 u) { return __uint_as_float(((u32)u) << 16); }
__device__ __forceinline__ u16 f2bf(float f) {
    u32 u = __float_as_uint(f);
    u32 r = (u + 0x7FFFu + ((u >> 16) & 1u)) >> 16;
    return (u16)r;
}
// order-preserving float->uint encoding for atomicMax
__device__ __forceinline__ u32 encf(float x) {
    int i = __float_as_int(x);
    return (i < 0) ? ~(u32)i : ((u32)i | 0x80000000u);
}
__device__ __forceinline__ float decf(u32 u) {
    int i = (u & 0x80000000u) ? (int)(u & 0x7FFFFFFFu) : (int)~u;
    return __int_as_float(i);
}

struct GSeg { const u16* base; const int* idx; int stride; int width; };
struct GSegs { GSeg s[5]; };
struct TSeg { int src_begin; int wreal; int wpad; };
struct TSegs { TSeg t[5]; };

// ---------------- generic gather-GEMM: C = relu(A_virtual @ BT^T + bias) ----------------
// A_virtual rows = concat of segments (gathered); BT is [Nout_padded][ldb] bf16 (pre-transposed W).
// STORE: write bf16 C.
// ATT:   atomicAdd per-row dot(C_row, attw) into attacc.
// FUSE:  atomicAdd per-row C_row@w2 (13 cols) into outf.
// SCAT:  atomicAdd scat_scale[row] * C_row into scat_out[scat_idx[row]] (fused aggregation).
template<int STORE, int ATT, int FUSE, int SCAT>
__global__ __launch_bounds__(256) void gemm_k(
    int M, int Nout, GSegs segs,
    const u16* __restrict__ BT, int ldb,
    const float* __restrict__ bias, int bias_n,
    u16* __restrict__ outb, int ldo,
    const float* __restrict__ attw, float* __restrict__ attacc,
    const float* __restrict__ w2, float* __restrict__ outf,
    const int* __restrict__ scat_idx, const float* __restrict__ scat_scale,
    float* __restrict__ scat_out, int scat_ld)
{
    __shared__ __align__(16) u16 As[128 * 40];
    __shared__ __align__(16) u16 Bs[128 * 40];
    const int tid = threadIdx.x;
    const int m0 = blockIdx.x * 128, n0 = blockIdx.y * 128;
    const int row = tid >> 1, half = tid & 1;
    int mrow = m0 + row; if (mrow >= M) mrow = M - 1;
    const int lane = tid & 63, wid = tid >> 6;
    const int wr = (wid >> 1) * 64, wc = (wid & 1) * 64;
    const int lr = lane & 15, lg = lane >> 4;

    f32x4 acc[4][4];
    for (int fm = 0; fm < 4; fm++)
        for (int fn = 0; fn < 4; fn++)
            acc[fm][fn] = f32x4{0.f, 0.f, 0.f, 0.f};

    const u16* brow = BT + (size_t)(n0 + row) * ldb + half * 16;

    auto do_step = [&](const u16* ga_, const u16* gb_) {
        float4 a0 = *(const float4*)ga_;
        float4 a1 = *(const float4*)(ga_ + 8);
        float4 b0 = *(const float4*)gb_;
        float4 b1 = *(const float4*)(gb_ + 8);
        __syncthreads();
        *(float4*)&As[row * 40 + half * 16]     = a0;
        *(float4*)&As[row * 40 + half * 16 + 8] = a1;
        *(float4*)&Bs[row * 40 + half * 16]     = b0;
        *(float4*)&Bs[row * 40 + half * 16 + 8] = b1;
        __syncthreads();
        bf16x8 af[4], bfv[4];
#pragma unroll
        for (int f = 0; f < 4; f++) {
            af[f]  = *(const bf16x8*)&As[(wr + f * 16 + lr) * 40 + lg * 8];
            bfv[f] = *(const bf16x8*)&Bs[(wc + f * 16 + lr) * 40 + lg * 8];
        }
#pragma unroll
        for (int fm = 0; fm < 4; fm++)
#pragma unroll
            for (int fn = 0; fn < 4; fn++)
                acc[fm][fn] = __builtin_amdgcn_mfma_f32_16x16x32_bf16(af[fm], bfv[fn], acc[fm][fn], 0, 0, 0);
    };

    int k0 = 0;
#pragma unroll
    for (int sI = 0; sI < 5; sI++) {
        const GSeg S = segs.s[sI];
        if (S.width > 0) {
            const int ridx = S.idx ? S.idx[mrow] : mrow;
            const u16* abase = S.base + (size_t)ridx * S.stride + half * 16;
            for (int kk = 0; kk < S.width; kk += 32) {
                do_step(abase + kk, brow + k0 + kk);
            }
            k0 += S.width;
        }
    }

    // epilogue
#pragma unroll
    for (int fm = 0; fm < 4; fm++) {
#pragma unroll
        for (int i = 0; i < 4; i++) {
            const int grow = m0 + wr + fm * 16 + lg * 4 + i;
            const bool rok = grow < M;
            float p[NCLS];
            if (FUSE) {
#pragma unroll
                for (int c = 0; c < NCLS; c++) p[c] = 0.f;
            }
            int sidx = 0; float ssc = 0.f;
            if (SCAT) {
                sidx = scat_idx[rok ? grow : 0];
                ssc = scat_scale[rok ? grow : 0];
            }
            float ap = 0.f;
#pragma unroll
            for (int fn = 0; fn < 4; fn++) {
                const int col = n0 + wc + fn * 16 + lr;
                float v = acc[fm][fn][i];
                v += (col < bias_n) ? bias[col] : 0.f;
                v = fmaxf(v, 0.f);
                if (STORE) {
                    if (rok && col < Nout) outb[(size_t)grow * ldo + col] = f2bf(v);
                }
                if (ATT) ap += v * attw[col];
                if (SCAT) {
                    if (rok && col < Nout)
                        atomicAdd(&scat_out[(size_t)sidx * scat_ld + col], ssc * v);
                }
                if (FUSE) {
#pragma unroll
                    for (int c = 0; c < NCLS; c++) p[c] += v * w2[col * NCLS + c];
                }
            }
            if (ATT) {
#pragma unroll
                for (int m_ = 1; m_ < 16; m_ <<= 1) ap += __shfl_xor(ap, m_, 64);
                if (lr == 0 && rok) atomicAdd(&attacc[grow], ap);
            }
            if (FUSE) {
#pragma unroll
                for (int c = 0; c < NCLS; c++) {
                    float pc = p[c];
#pragma unroll
                    for (int m_ = 1; m_ < 16; m_ <<= 1) pc += __shfl_xor(pc, m_, 64);
                    if (lr == 0 && rok) atomicAdd(&outf[(size_t)grow * NCLS + c], pc);
                }
            }
        }
    }
}

// ---------------- small kernels ----------------
__global__ __launch_bounds__(256) void cvt_bf(const float* __restrict__ src, u16* __restrict__ dst,
                                              int R, int Cs, int Cd)
{
    int id = blockIdx.x * 256 + threadIdx.x;
    if (id >= R * Cd) return;
    int r = id / Cd, c = id % Cd;
    float v = (c < Cs) ? src[(size_t)r * Cs + c] : 0.f;
    dst[id] = f2bf(v);
}

__global__ __launch_bounds__(256) void wtrans(const float* __restrict__ W, int Nw, int Nreal,
                                              int NrowsOut, int ldk, TSegs ts, int nseg,
                                              u16* __restrict__ WT)
{
    int id = blockIdx.x * 256 + threadIdx.x;
    if (id >= NrowsOut * ldk) return;
    int n = id / ldk, kp = id % ldk;
    float v = 0.f;
    if (n < Nreal) {
        int off = 0;
#pragma unroll
        for (int s = 0; s < 5; s++) {
            if (s < nseg) {
                int kl = kp - off;
                if (kl >= 0 && kl < ts.t[s].wpad) {
                    if (kl < ts.t[s].wreal) v = W[(size_t)(ts.t[s].src_begin + kl) * Nw + n];
                }
                off += ts.t[s].wpad;
            }
        }
    }
    WT[id] = f2bf(v);
}

__global__ __launch_bounds__(256) void att_fin(float* a, float* al, const float* ba, const float* bal, int E)
{
    int id = blockIdx.x * 256 + threadIdx.x;
    if (id >= E) return;
    float x = a[id] + ba[0];  a[id]  = x > 0.f ? x : 0.2f * x;
    float y = al[id] + bal[0]; al[id] = y > 0.f ? y : 0.2f * y;
}

__global__ __launch_bounds__(256) void segmax_k(const float* a, const float* al, const int* dst,
                                                u32* mu, u32* ml, int E)
{
    int id = blockIdx.x * 256 + threadIdx.x;
    if (id >= E) return;
    int d = dst[id];
    atomicMax(&mu[d], encf(a[id]));
    atomicMax(&ml[d], encf(al[id]));
}

__global__ __launch_bounds__(256) void expsum_k(float* a, float* al, const int* dst,
                                                const u32* mu, const u32* ml,
                                                float* s, float* sl, int E)
{
    int id = blockIdx.x * 256 + threadIdx.x;
    if (id >= E) return;
    int d = dst[id];
    float v = expf(a[id] - decf(mu[d]));  a[id] = v;  atomicAdd(&s[d], v);
    float w = expf(al[id] - decf(ml[d])); al[id] = w; atomicAdd(&sl[d], w);
}

__global__ __launch_bounds__(256) void alpha_k(float* a, float* al, const int* dst,
                                               const float* s, const float* sl, int E)
{
    int id = blockIdx.x * 256 + threadIdx.x;
    if (id >= E) return;
    int d = dst[id];
    a[id]  = a[id]  / (s[d]  + 1e-9f);
    al[id] = al[id] / (sl[d] + 1e-9f);
}

__global__ __launch_bounds__(256) void agg_zl(const float* __restrict__ w2v, const float* __restrict__ alphal,
                                              const int* __restrict__ src, const int* __restrict__ dst,
                                              float* __restrict__ zl, int E)
{
    int wv = blockIdx.x * 4 + (threadIdx.x >> 6);
    int lane = threadIdx.x & 63;
    if (wv >= E) return;
    float al = alphal[wv];
    int s = src[wv], d = dst[wv];
    for (int k = lane; k < DWR; k += 64)
        atomicAdd(&zl[(size_t)d * DWR + k], al * w2v[(size_t)s * DWR + k]);
}

__global__ __launch_bounds__(256) void addb_k(float* out, const float* __restrict__ b, int total)
{
    int id = blockIdx.x * 256 + threadIdx.x;
    if (id >= total) return;
    out[id] += b[id % NCLS];
}

__global__ __launch_bounds__(256) void diag_fill(float* out, int n, float v)
{
    int id = blockIdx.x * 256 + threadIdx.x;
    if (id < n) out[id] = v;
}

// ---------------- host ----------------
extern "C" void kernel_launch(void* const* d_in, const int* in_sizes, int n_in,
                              void* d_out, int out_size, void* d_ws, size_t ws_size,
                              hipStream_t stream)
{
    const float* n_f  = (const float*)d_in[0];
    const float* w2v  = (const float*)d_in[1];
    const float* s_f  = (const float*)d_in[2];
    const int*   src  = (const int*)d_in[3];
    const int*   dst  = (const int*)d_in[4];
    const float* W_e  = (const float*)d_in[5];
    const float* b_e  = (const float*)d_in[6];
    const float* W_el = (const float*)d_in[7];
    const float* b_el = (const float*)d_in[8];
    const float* W_a  = (const float*)d_in[9];
    const float* b_a  = (const float*)d_in[10];
    const float* W_al = (const float*)d_in[11];
    const float* b_al = (const float*)d_in[12];
    const float* W_n  = (const float*)d_in[13];
    const float* b_n  = (const float*)d_in[14];
    const float* W_nl = (const float*)d_in[15];
    const float* b_nl = (const float*)d_in[16];
    const float* W_r1 = (const float*)d_in[17];
    const float* b_r1 = (const float*)d_in[18];
    const float* W_r2 = (const float*)d_in[19];
    const float* b_r2 = (const float*)d_in[20];

    const int N = in_sizes[0] / ND;   // 20000
    const int E = in_sizes[3];        // 320000
    float* out = (float*)d_out;

    auto g1 = [](long long n) { return dim3((unsigned)((n + 255) / 256)); };

    char* base = (char*)d_ws;
    size_t off = 0;
    auto alloc = [&](size_t bytes) -> void* {
        void* r = base + off;
        off += (bytes + 255) & ~(size_t)255;
        return r;
    };
    u16* nf_bf = (u16*)alloc((size_t)N * ND * 2);
    u16* wv_bf = (u16*)alloc((size_t)N * DWP * 2);
    u16* sf_bf = (u16*)alloc((size_t)E * DSP * 2);
    u16* z_bf  = (u16*)alloc((size_t)N * ND * 2);
    u16* zl_bf = (u16*)alloc((size_t)N * DWP * 2);
    u16* WeT   = (u16*)alloc((size_t)512 * 1056 * 2);
    u16* WelT  = (u16*)alloc((size_t)512 * 640 * 2);
    u16* WnT   = (u16*)alloc((size_t)512 * 1024 * 2);
    u16* WnlT  = (u16*)alloc((size_t)384 * 640 * 2);
    u16* Wr1T  = (u16*)alloc((size_t)512 * 1696 * 2);
    float* aA  = (float*)alloc((size_t)E * 4);
    float* aL  = (float*)alloc((size_t)E * 4);
    float* sD  = (float*)alloc((size_t)N * 4);
    float* sLd = (float*)alloc((size_t)N * 4);
    u32* mU    = (u32*)alloc((size_t)N * 4);
    u32* mL    = (u32*)alloc((size_t)N * 4);
    float* z   = (float*)alloc((size_t)N * ND * 4);    // 41 MB fp32 accumulator
    float* zl  = (float*)alloc((size_t)N * DWR * 4);   // 24 MB fp32 accumulator
    // lifetime aliasing: z/zl are dead once converted to bf16; reuse for node-MLP outputs.
    u16* nn_bf = (u16*)z;
    u16* wn_bf = (u16*)zl;

    if (off > ws_size) {  // diagnostic: err ~= 2e6 next round means ws too small
        diag_fill<<<g1(out_size), 256, 0, stream>>>(out, out_size, 2.0e6f);
        return;
    }

    hipMemsetAsync(z,   0, (size_t)N * ND * 4, stream);
    hipMemsetAsync(zl,  0, (size_t)N * DWR * 4, stream);
    hipMemsetAsync(aA,  0, (size_t)E * 4, stream);
    hipMemsetAsync(aL,  0, (size_t)E * 4, stream);
    hipMemsetAsync(sD,  0, (size_t)N * 4, stream);
    hipMemsetAsync(sLd, 0, (size_t)N * 4, stream);
    hipMemsetAsync(mU,  0, (size_t)N * 4, stream);
    hipMemsetAsync(mL,  0, (size_t)N * 4, stream);
    hipMemsetAsync(out, 0, (size_t)out_size * 4, stream);

    cvt_bf<<<g1((long long)N * ND), 256, 0, stream>>>(n_f, nf_bf, N, ND, ND);
    cvt_bf<<<g1((long long)N * DWP), 256, 0, stream>>>(w2v, wv_bf, N, DWR, DWP);
    cvt_bf<<<g1((long long)E * DSP), 256, 0, stream>>>(s_f, sf_bf, E, DSR, DSP);

    { TSegs t{}; t.t[0] = {0,512,512}; t.t[1] = {528,512,512}; t.t[2] = {512,16,32};
      wtrans<<<g1(512 * 1056), 256, 0, stream>>>(W_e, 512, 512, 512, 1056, t, 3, WeT); }
    { TSegs t{}; t.t[0] = {0,300,320}; t.t[1] = {300,300,320};
      wtrans<<<g1(512 * 640), 256, 0, stream>>>(W_el, 512, 512, 512, 640, t, 2, WelT); }
    { TSegs t{}; t.t[0] = {0,512,512}; t.t[1] = {512,512,512};
      wtrans<<<g1(512 * 1024), 256, 0, stream>>>(W_n, 512, 512, 512, 1024, t, 2, WnT); }
    { TSegs t{}; t.t[0] = {0,300,320}; t.t[1] = {300,300,320};
      wtrans<<<g1(384 * 640), 256, 0, stream>>>(W_nl, 300, 300, 384, 640, t, 2, WnlT); }
    { TSegs t{}; t.t[0] = {0,512,512}; t.t[1] = {512,300,320}; t.t[2] = {812,16,32};
      t.t[3] = {828,300,320}; t.t[4] = {1128,512,512};
      wtrans<<<g1(512 * 1696), 256, 0, stream>>>(W_r1, 512, 512, 512, 1696, t, 5, Wr1T); }

    // edge MLP pass 1: attention logits only (no e_f materialization)
    { GSegs s{}; s.s[0] = {nf_bf, src, ND, 512}; s.s[1] = {nf_bf, dst, ND, 512}; s.s[2] = {sf_bf, nullptr, DSP, 32};
      gemm_k<0,1,0,0><<<dim3(E / 128, 4), 256, 0, stream>>>(E, 512, s, WeT, 1056, b_e, 512,
          nullptr, 0, W_a, aA, nullptr, nullptr, nullptr, nullptr, nullptr, 0); }
    // lang edge MLP: attention logits only
    { GSegs s{}; s.s[0] = {wv_bf, src, DWP, 320}; s.s[1] = {wv_bf, dst, DWP, 320};
      gemm_k<0,1,0,0><<<dim3(E / 128, 4), 256, 0, stream>>>(E, 512, s, WelT, 640, b_el, 512,
          nullptr, 0, W_al, aL, nullptr, nullptr, nullptr, nullptr, nullptr, 0); }

    att_fin<<<g1(E), 256, 0, stream>>>(aA, aL, b_a, b_al, E);
    segmax_k<<<g1(E), 256, 0, stream>>>(aA, aL, dst, mU, mL, E);
    expsum_k<<<g1(E), 256, 0, stream>>>(aA, aL, dst, mU, mL, sD, sLd, E);
    alpha_k<<<g1(E), 256, 0, stream>>>(aA, aL, dst, sD, sLd, E);

    // edge MLP pass 2: recompute e_f, scatter alpha*e_f into z (fused aggregation)
    { GSegs s{}; s.s[0] = {nf_bf, src, ND, 512}; s.s[1] = {nf_bf, dst, ND, 512}; s.s[2] = {sf_bf, nullptr, DSP, 32};
      gemm_k<0,0,0,1><<<dim3(E / 128, 4), 256, 0, stream>>>(E, 512, s, WeT, 1056, b_e, 512,
          nullptr, 0, nullptr, nullptr, nullptr, nullptr, dst, aA, z, ND); }
    agg_zl<<<dim3(E / 4), 256, 0, stream>>>(w2v, aL, src, dst, zl, E);

    cvt_bf<<<g1((long long)N * ND), 256, 0, stream>>>(z, z_bf, N, ND, ND);
    cvt_bf<<<g1((long long)N * DWP), 256, 0, stream>>>(zl, zl_bf, N, DWR, DWP);

    // node MLPs (outputs alias the now-dead fp32 accumulators)
    { GSegs s{}; s.s[0] = {nf_bf, nullptr, ND, 512}; s.s[1] = {z_bf, nullptr, ND, 512};
      gemm_k<1,0,0,0><<<dim3((N + 127) / 128, 4), 256, 0, stream>>>(N, 512, s, WnT, 1024, b_n, 512,
          nn_bf, 512, nullptr, nullptr, nullptr, nullptr, nullptr, nullptr, nullptr, 0); }
    { GSegs s{}; s.s[0] = {wv_bf, nullptr, DWP, 320}; s.s[1] = {zl_bf, nullptr, DWP, 320};
      gemm_k<1,0,0,0><<<dim3((N + 127) / 128, 3), 256, 0, stream>>>(N, 320, s, WnlT, 640, b_nl, 300,
          wn_bf, DWP, nullptr, nullptr, nullptr, nullptr, nullptr, nullptr, nullptr, 0); }

    // readout layer 1 + fused layer 2 (atomicAdd partials into d_out)
    { GSegs s{}; s.s[0] = {nn_bf, src, ND, 512}; s.s[1] = {wn_bf, src, DWP, 320}; s.s[2] = {sf_bf, nullptr, DSP, 32};
      s.s[3] = {wn_bf, dst, DWP, 320}; s.s[4] = {nn_bf, dst, ND, 512};
      gemm_k<0,0,1,0><<<dim3(E / 128, 4), 256, 0, stream>>>(E, 512, s, Wr1T, 1696, b_r1, 512,
          nullptr, 0, nullptr, nullptr, W_r2, out, nullptr, nullptr, nullptr, 0); }

    addb_k<<<g1((long long)E * NCLS), 256, 0, stream>>>(out, b_r2, E * NCLS);

    // diagnostic: any launch/config error -> err ~= 1e6+code next round
    hipError_t e = hipGetLastError();
    if (e != hipSuccess) {
        diag_fill<<<g1(out_size), 256, 0, stream>>>(out, out_size, 1.0e6f + (float)(int)e);
    }
}

// Round 3
// 4542.603 us; speedup vs baseline: 1.0711x; 1.0711x over previous
//
#include <hip/hip_runtime.h>

typedef unsigned short u16;
typedef unsigned int u32;
typedef __bf16 bf16x8 __attribute__((ext_vector_type(8)));
typedef float f32x4 __attribute__((ext_vector_type(4)));

#define ND 512
#define DWR 300
#define DWP 320
#define DSR 16
#define DSP 32
#define NCLS 13

__device__ __forceinline__ float bf2f(u16 u) { return __uint_as_float(((u32)u) << 16); }
__device__ __forceinline__ u16 f2bf(float f) {
    u32 u = __float_as_uint(f);
    u32 r = (u + 0x7FFFu + ((u >> 16) & 1u)) >> 16;
    return (u16)r;
}
__device__ __forceinline__ u32 encf(float x) {
    int i = __float_as_int(x);
    return (i < 0) ? ~(u32)i : ((u32)i | 0x80000000u);
}
__device__ __forceinline__ float decf(u32 u) {
    int i = (u & 0x80000000u) ? (int)(u & 0x7FFFFFFFu) : (int)~u;
    return __int_as_float(i);
}

struct GSeg { const u16* base; const int* idx; int stride; int width; };
struct GSegs { GSeg s[5]; };
struct TSeg { int src_begin; int wreal; int wpad; };
struct TSegs { TSeg t[5]; };

// ---------------- generic gather-GEMM: C = relu(A_virtual @ BT^T + bias) ----------------
// STORE: write bf16 C.
// ATT:   atomicAdd per-row dot(C_row, attw) into attacc.
// FUSE:  atomicAdd per-row C_row@w2 (13 cols) into outf[operm[row]] (restores original order).
// SEG:   rows sorted by scat_idx; LDS run-length reduce alpha*C_row into scat_out[scat_idx].
template<int STORE, int ATT, int FUSE, int SEG>
__global__ __launch_bounds__(256) void gemm_k(
    int M, int Nout, GSegs segs,
    const u16* __restrict__ BT, int ldb,
    const float* __restrict__ bias, int bias_n,
    u16* __restrict__ outb, int ldo,
    const float* __restrict__ attw, float* __restrict__ attacc,
    const float* __restrict__ w2, float* __restrict__ outf, const int* __restrict__ operm,
    const int* __restrict__ scat_idx, const float* __restrict__ scat_scale,
    float* __restrict__ scat_out, int scat_ld)
{
    __shared__ __align__(16) u16 smem[2 * 128 * 40];   // As | Bs (20480 B)
    u16* As = smem;
    u16* Bs = smem + 128 * 40;
    const int tid = threadIdx.x;

    // bijective XCD-friendly swizzle: the gy column-siblings of one x-tile get
    // dispatch ids that are 8 apart -> same XCD -> shared-A L2 hits.
    const int gx = gridDim.x, gy = gridDim.y;
    const int g0 = blockIdx.x + gx * blockIdx.y;
    int xt, yt;
    {
        const int fullg = gx >> 3;            // groups of 8 x-tiles
        const int gsz = 8 * gy;
        if (g0 < fullg * gsz) {
            const int grp = g0 / gsz, w = g0 % gsz;
            xt = grp * 8 + (w & 7); yt = w >> 3;
        } else {
            const int remx = gx - fullg * 8;  // 1..7 (only if gx%8 != 0)
            const int t = g0 - fullg * gsz;
            xt = fullg * 8 + t % remx; yt = t / remx;
        }
    }
    const int m0 = xt * 128, n0 = yt * 128;

    const int row = tid >> 1, half = tid & 1;
    int mrow = m0 + row; if (mrow >= M) mrow = M - 1;
    const int lane = tid & 63, wid = tid >> 6;
    const int wr = (wid >> 1) * 64, wc = (wid & 1) * 64;
    const int lr = lane & 15, lg = lane >> 4;

    f32x4 acc[4][4];
    for (int fm = 0; fm < 4; fm++)
        for (int fn = 0; fn < 4; fn++)
            acc[fm][fn] = f32x4{0.f, 0.f, 0.f, 0.f};

    const u16* brow = BT + (size_t)(n0 + row) * ldb + half * 16;

    auto do_step = [&](const u16* ga_, const u16* gb_) {
        float4 a0 = *(const float4*)ga_;
        float4 a1 = *(const float4*)(ga_ + 8);
        float4 b0 = *(const float4*)gb_;
        float4 b1 = *(const float4*)(gb_ + 8);
        __syncthreads();
        *(float4*)&As[row * 40 + half * 16]     = a0;
        *(float4*)&As[row * 40 + half * 16 + 8] = a1;
        *(float4*)&Bs[row * 40 + half * 16]     = b0;
        *(float4*)&Bs[row * 40 + half * 16 + 8] = b1;
        __syncthreads();
        bf16x8 af[4], bfv[4];
#pragma unroll
        for (int f = 0; f < 4; f++) {
            af[f]  = *(const bf16x8*)&As[(wr + f * 16 + lr) * 40 + lg * 8];
            bfv[f] = *(const bf16x8*)&Bs[(wc + f * 16 + lr) * 40 + lg * 8];
        }
#pragma unroll
        for (int fm = 0; fm < 4; fm++)
#pragma unroll
            for (int fn = 0; fn < 4; fn++)
                acc[fm][fn] = __builtin_amdgcn_mfma_f32_16x16x32_bf16(af[fm], bfv[fn], acc[fm][fn], 0, 0, 0);
    };

    int k0 = 0;
#pragma unroll
    for (int sI = 0; sI < 5; sI++) {
        const GSeg S = segs.s[sI];
        if (S.width > 0) {
            const int ridx = S.idx ? S.idx[mrow] : mrow;
            const u16* abase = S.base + (size_t)ridx * S.stride + half * 16;
            for (int kk = 0; kk < S.width; kk += 32) {
                do_step(abase + kk, brow + k0 + kk);
            }
            k0 += S.width;
        }
    }

    if (SEG) {
        // rows sorted by scat_idx: stage alpha*relu(acc+bias) to LDS per 32-row
        // chunk, then run-length reduce -> one atomicAdd per (dst-run, col).
        float* red = (float*)smem;                     // [32][129] f32 = 16512 B
        int* pd = (int*)((char*)smem + 16512);         // [32] int
        const int RP = 129;
#pragma unroll
        for (int c = 0; c < 4; ++c) {
            __syncthreads();
            if (tid < 32) pd[tid] = scat_idx[m0 + c * 32 + tid];
            if ((wid >> 1) == (c >> 1)) {
#pragma unroll
                for (int f2 = 0; f2 < 2; ++f2) {
                    const int fm = (c & 1) * 2 + f2;
#pragma unroll
                    for (int i = 0; i < 4; ++i) {
                        const int grow = m0 + wr + fm * 16 + lg * 4 + i;
                        const float ssc = scat_scale[grow];
#pragma unroll
                        for (int fn = 0; fn < 4; ++fn) {
                            const int col = n0 + wc + fn * 16 + lr;
                            float v = acc[fm][fn][i] + ((col < bias_n) ? bias[col] : 0.f);
                            v = fmaxf(v, 0.f);
                            red[(f2 * 16 + lg * 4 + i) * RP + (wc + fn * 16 + lr)] = ssc * v;
                        }
                    }
                }
            }
            __syncthreads();
            if (tid < 128) {
                const int colg = n0 + tid;
                float run = 0.f; int cur = pd[0];
                for (int r = 0; r < 32; ++r) {
                    run += red[r * RP + tid];
                    const int nxt = (r < 31) ? pd[r + 1] : -1;
                    if (nxt != cur) {
                        atomicAdd(&scat_out[(size_t)cur * scat_ld + colg], run);
                        run = 0.f; cur = nxt;
                    }
                }
            }
        }
        return;
    }

    // epilogue (STORE / ATT / FUSE)
#pragma unroll
    for (int fm = 0; fm < 4; fm++) {
#pragma unroll
        for (int i = 0; i < 4; i++) {
            const int grow = m0 + wr + fm * 16 + lg * 4 + i;
            const bool rok = grow < M;
            float p[NCLS];
            if (FUSE) {
#pragma unroll
                for (int c = 0; c < NCLS; c++) p[c] = 0.f;
            }
            float ap = 0.f;
#pragma unroll
            for (int fn = 0; fn < 4; fn++) {
                const int col = n0 + wc + fn * 16 + lr;
                float v = acc[fm][fn][i];
                v += (col < bias_n) ? bias[col] : 0.f;
                v = fmaxf(v, 0.f);
                if (STORE) {
                    if (rok && col < Nout) outb[(size_t)grow * ldo + col] = f2bf(v);
                }
                if (ATT) ap += v * attw[col];
                if (FUSE) {
#pragma unroll
                    for (int c = 0; c < NCLS; c++) p[c] += v * w2[col * NCLS + c];
                }
            }
            if (ATT) {
#pragma unroll
                for (int m_ = 1; m_ < 16; m_ <<= 1) ap += __shfl_xor(ap, m_, 64);
                if (lr == 0 && rok) atomicAdd(&attacc[grow], ap);
            }
            if (FUSE) {
                const int orow = rok ? operm[grow] : 0;
#pragma unroll
                for (int c = 0; c < NCLS; c++) {
                    float pc = p[c];
#pragma unroll
                    for (int m_ = 1; m_ < 16; m_ <<= 1) pc += __shfl_xor(pc, m_, 64);
                    if (lr == 0 && rok) atomicAdd(&outf[(size_t)orow * NCLS + c], pc);
                }
            }
        }
    }
}

// ---------------- small kernels ----------------
__global__ __launch_bounds__(256) void cvt_bf(const float* __restrict__ src, u16* __restrict__ dst,
                                              int R, int Cs, int Cd)
{
    int id = blockIdx.x * 256 + threadIdx.x;
    if (id >= R * Cd) return;
    int r = id / Cd, c = id % Cd;
    float v = (c < Cs) ? src[(size_t)r * Cs + c] : 0.f;
    dst[id] = f2bf(v);
}

__global__ __launch_bounds__(256) void wtrans(const float* __restrict__ W, int Nw, int Nreal,
                                              int NrowsOut, int ldk, TSegs ts, int nseg,
                                              u16* __restrict__ WT)
{
    int id = blockIdx.x * 256 + threadIdx.x;
    if (id >= NrowsOut * ldk) return;
    int n = id / ldk, kp = id % ldk;
    float v = 0.f;
    if (n < Nreal) {
        int off = 0;
#pragma unroll
        for (int s = 0; s < 5; s++) {
            if (s < nseg) {
                int kl = kp - off;
                if (kl >= 0 && kl < ts.t[s].wpad) {
                    if (kl < ts.t[s].wreal) v = W[(size_t)(ts.t[s].src_begin + kl) * Nw + n];
                }
                off += ts.t[s].wpad;
            }
        }
    }
    WT[id] = f2bf(v);
}

// --- counting sort by dst ---
__global__ __launch_bounds__(256) void hist_k(const int* __restrict__ dst, int* __restrict__ deg, int E)
{
    int id = blockIdx.x * 256 + threadIdx.x;
    if (id < E) atomicAdd(&deg[dst[id]], 1);
}

__global__ __launch_bounds__(1024) void scan_k(const int* __restrict__ deg,
                                               int* __restrict__ offs, int* __restrict__ cursor, int N)
{
    __shared__ int ps[1024];
    const int t = threadIdx.x;
    const int per = (N + 1023) >> 10;
    int s = 0;
    for (int j = 0; j < per; j++) { int idx = t * per + j; if (idx < N) s += deg[idx]; }
    ps[t] = s; __syncthreads();
    for (int o = 1; o < 1024; o <<= 1) {
        int v = (t >= o) ? ps[t - o] : 0; __syncthreads();
        ps[t] += v; __syncthreads();
    }
    int run = ps[t] - s;
    for (int j = 0; j < per; j++) {
        int idx = t * per + j;
        if (idx < N) { offs[idx] = run; cursor[idx] = run; run += deg[idx]; }
    }
}

__global__ __launch_bounds__(256) void scat_perm_k(const int* __restrict__ src, const int* __restrict__ dst,
                                                   int* __restrict__ cursor, int* __restrict__ perm,
                                                   int* __restrict__ psrc, int* __restrict__ pdst, int E)
{
    int id = blockIdx.x * 256 + threadIdx.x;
    if (id >= E) return;
    int d = dst[id];
    int pos = atomicAdd(&cursor[d], 1);
    perm[pos] = id; psrc[pos] = src[id]; pdst[pos] = d;
}

// --- softmax chain (sorted edge domain, seg = pdst) ---
__global__ __launch_bounds__(256) void att_fin(float* a, float* al, const float* ba, const float* bal, int E)
{
    int id = blockIdx.x * 256 + threadIdx.x;
    if (id >= E) return;
    float x = a[id] + ba[0];  a[id]  = x > 0.f ? x : 0.2f * x;
    float y = al[id] + bal[0]; al[id] = y > 0.f ? y : 0.2f * y;
}

__global__ __launch_bounds__(256) void segmax_k(const float* a, const float* al, const int* seg,
                                                u32* mu, u32* ml, int E)
{
    int id = blockIdx.x * 256 + threadIdx.x;
    if (id >= E) return;
    int d = seg[id];
    atomicMax(&mu[d], encf(a[id]));
    atomicMax(&ml[d], encf(al[id]));
}

__global__ __launch_bounds__(256) void expsum_k(float* a, float* al, const int* seg,
                                                const u32* mu, const u32* ml,
                                                float* s, float* sl, int E)
{
    int id = blockIdx.x * 256 + threadIdx.x;
    if (id >= E) return;
    int d = seg[id];
    float v = expf(a[id] - decf(mu[d]));  a[id] = v;  atomicAdd(&s[d], v);
    float w = expf(al[id] - decf(ml[d])); al[id] = w; atomicAdd(&sl[d], w);
}

__global__ __launch_bounds__(256) void alpha_k(float* a, float* al, const int* seg,
                                               const float* s, const float* sl, int E)
{
    int id = blockIdx.x * 256 + threadIdx.x;
    if (id >= E) return;
    int d = seg[id];
    a[id]  = a[id]  / (s[d]  + 1e-9f);
    al[id] = al[id] / (sl[d] + 1e-9f);
}

// --- z_l aggregation: one wave per node, zero atomics ---
__global__ __launch_bounds__(256) void agg_zl_seg(const u16* __restrict__ wv_bf,
                                                  const float* __restrict__ alphal,
                                                  const int* __restrict__ psrc,
                                                  const int* __restrict__ offs,
                                                  float* __restrict__ zl, int N, int E)
{
    const int node = blockIdx.x * 4 + (threadIdx.x >> 6);
    const int lane = threadIdx.x & 63;
    if (node >= N) return;
    const int e0 = offs[node];
    const int e1 = (node + 1 < N) ? offs[node + 1] : E;
    float acc[5] = {0.f, 0.f, 0.f, 0.f, 0.f};
    for (int e = e0; e < e1; ++e) {
        const float al = alphal[e];
        const u16* wr = wv_bf + (size_t)psrc[e] * DWP;
#pragma unroll
        for (int j = 0; j < 5; ++j) acc[j] += al * bf2f(wr[lane + 64 * j]);
    }
#pragma unroll
    for (int j = 0; j < 5; ++j) {
        const int c = lane + 64 * j;
        if (c < DWR) zl[(size_t)node * DWR + c] = acc[j];
    }
}

__global__ __launch_bounds__(256) void addb_k(float* out, const float* __restrict__ b, int total)
{
    int id = blockIdx.x * 256 + threadIdx.x;
    if (id >= total) return;
    out[id] += b[id % NCLS];
}

__global__ __launch_bounds__(256) void diag_fill(float* out, int n, float v)
{
    int id = blockIdx.x * 256 + threadIdx.x;
    if (id < n) out[id] = v;
}

// ---------------- host ----------------
extern "C" void kernel_launch(void* const* d_in, const int* in_sizes, int n_in,
                              void* d_out, int out_size, void* d_ws, size_t ws_size,
                              hipStream_t stream)
{
    const float* n_f  = (const float*)d_in[0];
    const float* w2v  = (const float*)d_in[1];
    const float* s_f  = (const float*)d_in[2];
    const int*   src  = (const int*)d_in[3];
    const int*   dst  = (const int*)d_in[4];
    const float* W_e  = (const float*)d_in[5];
    const float* b_e  = (const float*)d_in[6];
    const float* W_el = (const float*)d_in[7];
    const float* b_el = (const float*)d_in[8];
    const float* W_a  = (const float*)d_in[9];
    const float* b_a  = (const float*)d_in[10];
    const float* W_al = (const float*)d_in[11];
    const float* b_al = (const float*)d_in[12];
    const float* W_n  = (const float*)d_in[13];
    const float* b_n  = (const float*)d_in[14];
    const float* W_nl = (const float*)d_in[15];
    const float* b_nl = (const float*)d_in[16];
    const float* W_r1 = (const float*)d_in[17];
    const float* b_r1 = (const float*)d_in[18];
    const float* W_r2 = (const float*)d_in[19];
    const float* b_r2 = (const float*)d_in[20];

    const int N = in_sizes[0] / ND;   // 20000
    const int E = in_sizes[3];        // 320000
    float* out = (float*)d_out;

    auto g1 = [](long long n) { return dim3((unsigned)((n + 255) / 256)); };

    char* base = (char*)d_ws;
    size_t off = 0;
    auto alloc = [&](size_t bytes) -> void* {
        void* r = base + off;
        off += (bytes + 255) & ~(size_t)255;
        return r;
    };
    u16* nf_bf = (u16*)alloc((size_t)N * ND * 2);
    u16* wv_bf = (u16*)alloc((size_t)N * DWP * 2);
    u16* sf_bf = (u16*)alloc((size_t)E * DSP * 2);
    u16* z_bf  = (u16*)alloc((size_t)N * ND * 2);
    u16* zl_bf = (u16*)alloc((size_t)N * DWP * 2);
    u16* WeT   = (u16*)alloc((size_t)512 * 1056 * 2);
    u16* WelT  = (u16*)alloc((size_t)512 * 640 * 2);
    u16* WnT   = (u16*)alloc((size_t)512 * 1024 * 2);
    u16* WnlT  = (u16*)alloc((size_t)384 * 640 * 2);
    u16* Wr1T  = (u16*)alloc((size_t)512 * 1696 * 2);
    float* aAs = (float*)alloc((size_t)E * 4);   // logits/alpha, sorted order
    float* aLs = (float*)alloc((size_t)E * 4);
    float* sD  = (float*)alloc((size_t)N * 4);
    float* sLd = (float*)alloc((size_t)N * 4);
    u32* mU    = (u32*)alloc((size_t)N * 4);
    u32* mL    = (u32*)alloc((size_t)N * 4);
    float* z   = (float*)alloc((size_t)N * ND * 4);
    float* zl  = (float*)alloc((size_t)N * DWR * 4);
    int* deg    = (int*)alloc((size_t)N * 4);
    int* offs   = (int*)alloc((size_t)N * 4);
    int* cursor = (int*)alloc((size_t)N * 4);
    int* perm   = (int*)alloc((size_t)E * 4);
    int* psrc   = (int*)alloc((size_t)E * 4);
    int* pdst   = (int*)alloc((size_t)E * 4);
    // lifetime aliasing: z/zl dead after cvt; reuse for node-MLP outputs.
    u16* nn_bf = (u16*)z;
    u16* wn_bf = (u16*)zl;

    if (off > ws_size) {
        diag_fill<<<g1(out_size), 256, 0, stream>>>(out, out_size, 2.0e6f);
        return;
    }

    hipMemsetAsync(z,   0, (size_t)N * ND * 4, stream);
    hipMemsetAsync(aAs, 0, (size_t)E * 4, stream);
    hipMemsetAsync(aLs, 0, (size_t)E * 4, stream);
    hipMemsetAsync(sD,  0, (size_t)N * 4, stream);
    hipMemsetAsync(sLd, 0, (size_t)N * 4, stream);
    hipMemsetAsync(mU,  0, (size_t)N * 4, stream);
    hipMemsetAsync(mL,  0, (size_t)N * 4, stream);
    hipMemsetAsync(deg, 0, (size_t)N * 4, stream);
    hipMemsetAsync(out, 0, (size_t)out_size * 4, stream);

    // sort edges by dst
    hist_k<<<g1(E), 256, 0, stream>>>(dst, deg, E);
    scan_k<<<dim3(1), 1024, 0, stream>>>(deg, offs, cursor, N);
    scat_perm_k<<<g1(E), 256, 0, stream>>>(src, dst, cursor, perm, psrc, pdst, E);

    cvt_bf<<<g1((long long)N * ND), 256, 0, stream>>>(n_f, nf_bf, N, ND, ND);
    cvt_bf<<<g1((long long)N * DWP), 256, 0, stream>>>(w2v, wv_bf, N, DWR, DWP);
    cvt_bf<<<g1((long long)E * DSP), 256, 0, stream>>>(s_f, sf_bf, E, DSR, DSP);

    { TSegs t{}; t.t[0] = {0,512,512}; t.t[1] = {528,512,512}; t.t[2] = {512,16,32};
      wtrans<<<g1(512 * 1056), 256, 0, stream>>>(W_e, 512, 512, 512, 1056, t, 3, WeT); }
    { TSegs t{}; t.t[0] = {0,300,320}; t.t[1] = {300,300,320};
      wtrans<<<g1(512 * 640), 256, 0, stream>>>(W_el, 512, 512, 512, 640, t, 2, WelT); }
    { TSegs t{}; t.t[0] = {0,512,512}; t.t[1] = {512,512,512};
      wtrans<<<g1(512 * 1024), 256, 0, stream>>>(W_n, 512, 512, 512, 1024, t, 2, WnT); }
    { TSegs t{}; t.t[0] = {0,300,320}; t.t[1] = {300,300,320};
      wtrans<<<g1(384 * 640), 256, 0, stream>>>(W_nl, 300, 300, 384, 640, t, 2, WnlT); }
    { TSegs t{}; t.t[0] = {0,512,512}; t.t[1] = {512,300,320}; t.t[2] = {812,16,32};
      t.t[3] = {828,300,320}; t.t[4] = {1128,512,512};
      wtrans<<<g1(512 * 1696), 256, 0, stream>>>(W_r1, 512, 512, 512, 1696, t, 5, Wr1T); }

    // edge MLP pass 1 (sorted rows): attention logits only
    { GSegs s{}; s.s[0] = {nf_bf, psrc, ND, 512}; s.s[1] = {nf_bf, pdst, ND, 512}; s.s[2] = {sf_bf, perm, DSP, 32};
      gemm_k<0,1,0,0><<<dim3(E / 128, 4), 256, 0, stream>>>(E, 512, s, WeT, 1056, b_e, 512,
          nullptr, 0, W_a, aAs, nullptr, nullptr, nullptr, nullptr, nullptr, nullptr, 0); }
    // lang edge MLP (sorted rows): attention logits only
    { GSegs s{}; s.s[0] = {wv_bf, psrc, DWP, 320}; s.s[1] = {wv_bf, pdst, DWP, 320};
      gemm_k<0,1,0,0><<<dim3(E / 128, 4), 256, 0, stream>>>(E, 512, s, WelT, 640, b_el, 512,
          nullptr, 0, W_al, aLs, nullptr, nullptr, nullptr, nullptr, nullptr, nullptr, 0); }

    att_fin<<<g1(E), 256, 0, stream>>>(aAs, aLs, b_a, b_al, E);
    segmax_k<<<g1(E), 256, 0, stream>>>(aAs, aLs, pdst, mU, mL, E);
    expsum_k<<<g1(E), 256, 0, stream>>>(aAs, aLs, pdst, mU, mL, sD, sLd, E);
    alpha_k<<<g1(E), 256, 0, stream>>>(aAs, aLs, pdst, sD, sLd, E);

    // edge MLP pass 2: recompute e_f, segment-reduce alpha*e_f into z
    { GSegs s{}; s.s[0] = {nf_bf, psrc, ND, 512}; s.s[1] = {nf_bf, pdst, ND, 512}; s.s[2] = {sf_bf, perm, DSP, 32};
      gemm_k<0,0,0,1><<<dim3(E / 128, 4), 256, 0, stream>>>(E, 512, s, WeT, 1056, b_e, 512,
          nullptr, 0, nullptr, nullptr, nullptr, nullptr, nullptr, pdst, aAs, z, ND); }
    // z_l aggregation: per-node gather, no atomics
    agg_zl_seg<<<dim3((N + 3) / 4), 256, 0, stream>>>(wv_bf, aLs, psrc, offs, zl, N, E);

    cvt_bf<<<g1((long long)N * ND), 256, 0, stream>>>(z, z_bf, N, ND, ND);
    cvt_bf<<<g1((long long)N * DWP), 256, 0, stream>>>(zl, zl_bf, N, DWR, DWP);

    // node MLPs
    { GSegs s{}; s.s[0] = {nf_bf, nullptr, ND, 512}; s.s[1] = {z_bf, nullptr, ND, 512};
      gemm_k<1,0,0,0><<<dim3((N + 127) / 128, 4), 256, 0, stream>>>(N, 512, s, WnT, 1024, b_n, 512,
          nn_bf, 512, nullptr, nullptr, nullptr, nullptr, nullptr, nullptr, nullptr, nullptr, 0); }
    { GSegs s{}; s.s[0] = {wv_bf, nullptr, DWP, 320}; s.s[1] = {zl_bf, nullptr, DWP, 320};
      gemm_k<1,0,0,0><<<dim3((N + 127) / 128, 3), 256, 0, stream>>>(N, 320, s, WnlT, 640, b_nl, 300,
          wn_bf, DWP, nullptr, nullptr, nullptr, nullptr, nullptr, nullptr, nullptr, nullptr, 0); }

    // readout layer 1 + fused layer 2 (sorted rows; scatter to original order via perm)
    { GSegs s{}; s.s[0] = {nn_bf, psrc, ND, 512}; s.s[1] = {wn_bf, psrc, DWP, 320}; s.s[2] = {sf_bf, perm, DSP, 32};
      s.s[3] = {wn_bf, pdst, DWP, 320}; s.s[4] = {nn_bf, pdst, ND, 512};
      gemm_k<0,0,1,0><<<dim3(E / 128, 4), 256, 0, stream>>>(E, 512, s, Wr1T, 1696, b_r1, 512,
          nullptr, 0, nullptr, nullptr, W_r2, out, perm, nullptr, nullptr, nullptr, 0); }

    addb_k<<<g1((long long)E * NCLS), 256, 0, stream>>>(out, b_r2, E * NCLS);

    hipError_t e = hipGetLastError();
    if (e != hipSuccess) {
        diag_fill<<<g1(out_size), 256, 0, stream>>>(out, out_size, 1.0e6f + (float)(int)e);
    }
}

// Round 4
// 3435.830 us; speedup vs baseline: 1.4162x; 1.3221x over previous
//
#include <hip/hip_runtime.h>

typedef unsigned short u16;
typedef unsigned int u32;
typedef __bf16 bf16x8 __attribute__((ext_vector_type(8)));
typedef float f32x4 __attribute__((ext_vector_type(4)));

#define ND 512
#define DWR 300
#define DWP 320
#define DSR 16
#define DSP 32
#define NCLS 13

__device__ __forceinline__ float bf2f(u16 u) { return __uint_as_float(((u32)u) << 16); }
__device__ __forceinline__ u16 f2bf(float f) {
    u32 u = __float_as_uint(f);
    u32 r = (u + 0x7FFFu + ((u >> 16) & 1u)) >> 16;
    return (u16)r;
}
__device__ __forceinline__ u32 encf(float x) {
    int i = __float_as_int(x);
    return (i < 0) ? ~(u32)i : ((u32)i | 0x80000000u);
}
__device__ __forceinline__ float decf(u32 u) {
    int i = (u & 0x80000000u) ? (int)(u & 0x7FFFFFFFu) : (int)~u;
    return __int_as_float(i);
}

struct GSeg { const u16* base; const int* idx; int stride; int width; };
struct GSegs { GSeg s[5]; };
struct TSeg { int src_begin; int wreal; int wpad; };
struct TSegs { TSeg t[5]; };

// ---------------- generic gather-GEMM: C = relu(A_virtual @ BT^T + bias) ----------------
// STORE: write bf16 C.
// ATT:   atomicAdd per-row dot(C_row, attw) into attacc.
// SEG:   rows sorted by scat_idx; LDS run-length reduce alpha*C_row into scat_out[scat_idx].
template<int STORE, int ATT, int SEG>
__global__ __launch_bounds__(256) void gemm_k(
    int M, int Nout, GSegs segs,
    const u16* __restrict__ BT, int ldb,
    const float* __restrict__ bias, int bias_n,
    u16* __restrict__ outb, int ldo,
    const float* __restrict__ attw, float* __restrict__ attacc,
    const int* __restrict__ scat_idx, const float* __restrict__ scat_scale,
    float* __restrict__ scat_out, int scat_ld)
{
    __shared__ __align__(16) u16 smem[2 * 128 * 40];   // As | Bs (20480 B)
    u16* As = smem;
    u16* Bs = smem + 128 * 40;
    const int tid = threadIdx.x;

    // bijective XCD-friendly swizzle: the gy column-siblings of one x-tile get
    // dispatch ids that are 8 apart -> same XCD -> shared-A L2 hits.
    const int gx = gridDim.x, gy = gridDim.y;
    const int g0 = blockIdx.x + gx * blockIdx.y;
    int xt, yt;
    {
        const int fullg = gx >> 3;            // groups of 8 x-tiles
        const int gsz = 8 * gy;
        if (g0 < fullg * gsz) {
            const int grp = g0 / gsz, w = g0 % gsz;
            xt = grp * 8 + (w & 7); yt = w >> 3;
        } else {
            const int remx = gx - fullg * 8;  // 1..7 (only if gx%8 != 0)
            const int t = g0 - fullg * gsz;
            xt = fullg * 8 + t % remx; yt = t / remx;
        }
    }
    const int m0 = xt * 128, n0 = yt * 128;

    const int row = tid >> 1, half = tid & 1;
    int mrow = m0 + row; if (mrow >= M) mrow = M - 1;
    const int lane = tid & 63, wid = tid >> 6;
    const int wr = (wid >> 1) * 64, wc = (wid & 1) * 64;
    const int lr = lane & 15, lg = lane >> 4;

    f32x4 acc[4][4];
    for (int fm = 0; fm < 4; fm++)
        for (int fn = 0; fn < 4; fn++)
            acc[fm][fn] = f32x4{0.f, 0.f, 0.f, 0.f};

    const u16* brow = BT + (size_t)(n0 + row) * ldb + half * 16;

    auto do_step = [&](const u16* ga_, const u16* gb_) {
        float4 a0 = *(const float4*)ga_;
        float4 a1 = *(const float4*)(ga_ + 8);
        float4 b0 = *(const float4*)gb_;
        float4 b1 = *(const float4*)(gb_ + 8);
        __syncthreads();
        *(float4*)&As[row * 40 + half * 16]     = a0;
        *(float4*)&As[row * 40 + half * 16 + 8] = a1;
        *(float4*)&Bs[row * 40 + half * 16]     = b0;
        *(float4*)&Bs[row * 40 + half * 16 + 8] = b1;
        __syncthreads();
        bf16x8 af[4], bfv[4];
#pragma unroll
        for (int f = 0; f < 4; f++) {
            af[f]  = *(const bf16x8*)&As[(wr + f * 16 + lr) * 40 + lg * 8];
            bfv[f] = *(const bf16x8*)&Bs[(wc + f * 16 + lr) * 40 + lg * 8];
        }
#pragma unroll
        for (int fm = 0; fm < 4; fm++)
#pragma unroll
            for (int fn = 0; fn < 4; fn++)
                acc[fm][fn] = __builtin_amdgcn_mfma_f32_16x16x32_bf16(af[fm], bfv[fn], acc[fm][fn], 0, 0, 0);
    };

    int k0 = 0;
#pragma unroll
    for (int sI = 0; sI < 5; sI++) {
        const GSeg S = segs.s[sI];
        if (S.width > 0) {
            const int ridx = S.idx ? S.idx[mrow] : mrow;
            const u16* abase = S.base + (size_t)ridx * S.stride + half * 16;
            for (int kk = 0; kk < S.width; kk += 32) {
                do_step(abase + kk, brow + k0 + kk);
            }
            k0 += S.width;
        }
    }

    if (SEG) {
        // rows sorted by scat_idx: stage alpha*relu(acc+bias) to LDS per 32-row
        // chunk, then run-length reduce -> one atomicAdd per (dst-run, col).
        float* red = (float*)smem;                     // [32][129] f32 = 16512 B
        int* pd = (int*)((char*)smem + 16512);         // [32] int
        const int RP = 129;
#pragma unroll
        for (int c = 0; c < 4; ++c) {
            __syncthreads();
            if (tid < 32) pd[tid] = scat_idx[m0 + c * 32 + tid];
            if ((wid >> 1) == (c >> 1)) {
#pragma unroll
                for (int f2 = 0; f2 < 2; ++f2) {
                    const int fm = (c & 1) * 2 + f2;
#pragma unroll
                    for (int i = 0; i < 4; ++i) {
                        const int grow = m0 + wr + fm * 16 + lg * 4 + i;
                        const float ssc = scat_scale[grow];
#pragma unroll
                        for (int fn = 0; fn < 4; ++fn) {
                            const int col = n0 + wc + fn * 16 + lr;
                            float v = acc[fm][fn][i] + ((col < bias_n) ? bias[col] : 0.f);
                            v = fmaxf(v, 0.f);
                            red[(f2 * 16 + lg * 4 + i) * RP + (wc + fn * 16 + lr)] = ssc * v;
                        }
                    }
                }
            }
            __syncthreads();
            if (tid < 128) {
                const int colg = n0 + tid;
                float run = 0.f; int cur = pd[0];
                for (int r = 0; r < 32; ++r) {
                    run += red[r * RP + tid];
                    const int nxt = (r < 31) ? pd[r + 1] : -1;
                    if (nxt != cur) {
                        atomicAdd(&scat_out[(size_t)cur * scat_ld + colg], run);
                        run = 0.f; cur = nxt;
                    }
                }
            }
        }
        return;
    }

    // epilogue (STORE / ATT)
#pragma unroll
    for (int fm = 0; fm < 4; fm++) {
#pragma unroll
        for (int i = 0; i < 4; i++) {
            const int grow = m0 + wr + fm * 16 + lg * 4 + i;
            const bool rok = grow < M;
            float ap = 0.f;
#pragma unroll
            for (int fn = 0; fn < 4; fn++) {
                const int col = n0 + wc + fn * 16 + lr;
                float v = acc[fm][fn][i];
                v += (col < bias_n) ? bias[col] : 0.f;
                v = fmaxf(v, 0.f);
                if (STORE) {
                    if (rok && col < Nout) outb[(size_t)grow * ldo + col] = f2bf(v);
                }
                if (ATT) ap += v * attw[col];
            }
            if (ATT) {
#pragma unroll
                for (int m_ = 1; m_ < 16; m_ <<= 1) ap += __shfl_xor(ap, m_, 64);
                if (lr == 0 && rok) atomicAdd(&attacc[grow], ap);
            }
        }
    }
}

// ---------------- readout: full row in one block, zero global atomics ----------------
// Iterates the 4 col-blocks sequentially, accumulating p[row][13] in LDS;
// ends with a single plain store per output element (original edge order via operm).
__global__ __launch_bounds__(256) void readout_k(
    int M, GSegs segs,
    const u16* __restrict__ BT, int ldb,
    const float* __restrict__ bias,
    const float* __restrict__ w2,        // [512][13] fp32
    const int* __restrict__ operm,
    float* __restrict__ outf)
{
    __shared__ __align__(16) u16 As[128 * 40];
    __shared__ __align__(16) u16 Bs[128 * 40];
    __shared__ float w2s[128 * NCLS];
    __shared__ float pacc[128 * NCLS];

    const int tid = threadIdx.x;
    // bijective 1-D XCD swizzle (m204): consecutive xt land on the same XCD.
    int xt;
    {
        const int gx = gridDim.x;
        const int q = gx >> 3, r = gx & 7;
        const int x = blockIdx.x & 7, o = blockIdx.x >> 3;
        xt = (x < r ? x * (q + 1) : r * (q + 1) + (x - r) * q) + o;
    }
    const int m0 = xt * 128;

    const int row = tid >> 1, half = tid & 1;
    int mrow = m0 + row; if (mrow >= M) mrow = M - 1;
    const int lane = tid & 63, wid = tid >> 6;
    const int wr = (wid >> 1) * 64, wc = (wid & 1) * 64;
    const int lr = lane & 15, lg = lane >> 4;

    // gathered A row bases (fixed across col-blocks)
    const u16* abase[5];
#pragma unroll
    for (int sI = 0; sI < 5; sI++) {
        const GSeg S = segs.s[sI];
        const int ridx = S.idx ? S.idx[mrow] : mrow;
        abase[sI] = S.base + (size_t)ridx * S.stride + half * 16;
    }

    for (int i = tid; i < 128 * NCLS; i += 256) pacc[i] = 0.f;

    for (int yb = 0; yb < 4; ++yb) {
        const int n0 = yb * 128;
        __syncthreads();   // pacc/w2s readers from previous iteration done
        for (int i = tid; i < 128 * NCLS; i += 256) w2s[i] = w2[n0 * NCLS + i];

        f32x4 acc[4][4];
#pragma unroll
        for (int fm = 0; fm < 4; fm++)
#pragma unroll
            for (int fn = 0; fn < 4; fn++)
                acc[fm][fn] = f32x4{0.f, 0.f, 0.f, 0.f};

        const u16* brow = BT + (size_t)(n0 + row) * ldb + half * 16;

        int k0 = 0;
#pragma unroll
        for (int sI = 0; sI < 5; sI++) {
            const GSeg S = segs.s[sI];
            const u16* ab = abase[sI];
            for (int kk = 0; kk < S.width; kk += 32) {
                float4 a0 = *(const float4*)(ab + kk);
                float4 a1 = *(const float4*)(ab + kk + 8);
                float4 b0 = *(const float4*)(brow + k0 + kk);
                float4 b1 = *(const float4*)(brow + k0 + kk + 8);
                __syncthreads();
                *(float4*)&As[row * 40 + half * 16]     = a0;
                *(float4*)&As[row * 40 + half * 16 + 8] = a1;
                *(float4*)&Bs[row * 40 + half * 16]     = b0;
                *(float4*)&Bs[row * 40 + half * 16 + 8] = b1;
                __syncthreads();
                bf16x8 af[4], bfv[4];
#pragma unroll
                for (int f = 0; f < 4; f++) {
                    af[f]  = *(const bf16x8*)&As[(wr + f * 16 + lr) * 40 + lg * 8];
                    bfv[f] = *(const bf16x8*)&Bs[(wc + f * 16 + lr) * 40 + lg * 8];
                }
#pragma unroll
                for (int fm = 0; fm < 4; fm++)
#pragma unroll
                    for (int fn = 0; fn < 4; fn++)
                        acc[fm][fn] = __builtin_amdgcn_mfma_f32_16x16x32_bf16(af[fm], bfv[fn], acc[fm][fn], 0, 0, 0);
            }
            k0 += S.width;
        }

        // partial epilogue: p[row] += relu(acc+bias) @ w2_slice  (LDS accumulate)
#pragma unroll
        for (int fm = 0; fm < 4; fm++) {
#pragma unroll
            for (int i = 0; i < 4; i++) {
                const int rt = wr + fm * 16 + lg * 4 + i;   // 0..127
                float p[NCLS];
#pragma unroll
                for (int c = 0; c < NCLS; c++) p[c] = 0.f;
#pragma unroll
                for (int fn = 0; fn < 4; fn++) {
                    const int cl = wc + fn * 16 + lr;       // 0..127
                    float v = acc[fm][fn][i] + bias[n0 + cl];
                    v = fmaxf(v, 0.f);
#pragma unroll
                    for (int c = 0; c < NCLS; c++) p[c] += v * w2s[cl * NCLS + c];
                }
#pragma unroll
                for (int c = 0; c < NCLS; c++) {
#pragma unroll
                    for (int m_ = 1; m_ < 16; m_ <<= 1) p[c] += __shfl_xor(p[c], m_, 64);
                }
                if (lr == 0) {
#pragma unroll
                    for (int c = 0; c < NCLS; c++) atomicAdd(&pacc[rt * NCLS + c], p[c]);
                }
            }
        }
    }

    __syncthreads();
    for (int i = tid; i < 128 * NCLS; i += 256) {
        const int r = i / NCLS, c = i - r * NCLS;
        const int grow = m0 + r;
        if (grow < M) outf[(size_t)operm[grow] * NCLS + c] = pacc[i];
    }
}

// ---------------- small kernels ----------------
__global__ __launch_bounds__(256) void cvt_bf(const float* __restrict__ src, u16* __restrict__ dst,
                                              int R, int Cs, int Cd)
{
    int id = blockIdx.x * 256 + threadIdx.x;
    if (id >= R * Cd) return;
    int r = id / Cd, c = id % Cd;
    float v = (c < Cs) ? src[(size_t)r * Cs + c] : 0.f;
    dst[id] = f2bf(v);
}

__global__ __launch_bounds__(256) void wtrans(const float* __restrict__ W, int Nw, int Nreal,
                                              int NrowsOut, int ldk, TSegs ts, int nseg,
                                              u16* __restrict__ WT)
{
    int id = blockIdx.x * 256 + threadIdx.x;
    if (id >= NrowsOut * ldk) return;
    int n = id / ldk, kp = id % ldk;
    float v = 0.f;
    if (n < Nreal) {
        int off = 0;
#pragma unroll
        for (int s = 0; s < 5; s++) {
            if (s < nseg) {
                int kl = kp - off;
                if (kl >= 0 && kl < ts.t[s].wpad) {
                    if (kl < ts.t[s].wreal) v = W[(size_t)(ts.t[s].src_begin + kl) * Nw + n];
                }
                off += ts.t[s].wpad;
            }
        }
    }
    WT[id] = f2bf(v);
}

// --- counting sort by dst ---
__global__ __launch_bounds__(256) void hist_k(const int* __restrict__ dst, int* __restrict__ deg, int E)
{
    int id = blockIdx.x * 256 + threadIdx.x;
    if (id < E) atomicAdd(&deg[dst[id]], 1);
}

__global__ __launch_bounds__(1024) void scan_k(const int* __restrict__ deg,
                                               int* __restrict__ offs, int* __restrict__ cursor, int N)
{
    __shared__ int ps[1024];
    const int t = threadIdx.x;
    const int per = (N + 1023) >> 10;
    int s = 0;
    for (int j = 0; j < per; j++) { int idx = t * per + j; if (idx < N) s += deg[idx]; }
    ps[t] = s; __syncthreads();
    for (int o = 1; o < 1024; o <<= 1) {
        int v = (t >= o) ? ps[t - o] : 0; __syncthreads();
        ps[t] += v; __syncthreads();
    }
    int run = ps[t] - s;
    for (int j = 0; j < per; j++) {
        int idx = t * per + j;
        if (idx < N) { offs[idx] = run; cursor[idx] = run; run += deg[idx]; }
    }
}

__global__ __launch_bounds__(256) void scat_perm_k(const int* __restrict__ src, const int* __restrict__ dst,
                                                   int* __restrict__ cursor, int* __restrict__ perm,
                                                   int* __restrict__ psrc, int* __restrict__ pdst, int E)
{
    int id = blockIdx.x * 256 + threadIdx.x;
    if (id >= E) return;
    int d = dst[id];
    int pos = atomicAdd(&cursor[d], 1);
    perm[pos] = id; psrc[pos] = src[id]; pdst[pos] = d;
}

// --- softmax chain (sorted edge domain, seg = pdst) ---
__global__ __launch_bounds__(256) void att_fin(float* a, float* al, const float* ba, const float* bal, int E)
{
    int id = blockIdx.x * 256 + threadIdx.x;
    if (id >= E) return;
    float x = a[id] + ba[0];  a[id]  = x > 0.f ? x : 0.2f * x;
    float y = al[id] + bal[0]; al[id] = y > 0.f ? y : 0.2f * y;
}

__global__ __launch_bounds__(256) void segmax_k(const float* a, const float* al, const int* seg,
                                                u32* mu, u32* ml, int E)
{
    int id = blockIdx.x * 256 + threadIdx.x;
    if (id >= E) return;
    int d = seg[id];
    atomicMax(&mu[d], encf(a[id]));
    atomicMax(&ml[d], encf(al[id]));
}

__global__ __launch_bounds__(256) void expsum_k(float* a, float* al, const int* seg,
                                                const u32* mu, const u32* ml,
                                                float* s, float* sl, int E)
{
    int id = blockIdx.x * 256 + threadIdx.x;
    if (id >= E) return;
    int d = seg[id];
    float v = expf(a[id] - decf(mu[d]));  a[id] = v;  atomicAdd(&s[d], v);
    float w = expf(al[id] - decf(ml[d])); al[id] = w; atomicAdd(&sl[d], w);
}

__global__ __launch_bounds__(256) void alpha_k(float* a, float* al, const int* seg,
                                               const float* s, const float* sl, int E)
{
    int id = blockIdx.x * 256 + threadIdx.x;
    if (id >= E) return;
    int d = seg[id];
    a[id]  = a[id]  / (s[d]  + 1e-9f);
    al[id] = al[id] / (sl[d] + 1e-9f);
}

// --- z_l aggregation: one wave per node, zero atomics ---
__global__ __launch_bounds__(256) void agg_zl_seg(const u16* __restrict__ wv_bf,
                                                  const float* __restrict__ alphal,
                                                  const int* __restrict__ psrc,
                                                  const int* __restrict__ offs,
                                                  float* __restrict__ zl, int N, int E)
{
    const int node = blockIdx.x * 4 + (threadIdx.x >> 6);
    const int lane = threadIdx.x & 63;
    if (node >= N) return;
    const int e0 = offs[node];
    const int e1 = (node + 1 < N) ? offs[node + 1] : E;
    float acc[5] = {0.f, 0.f, 0.f, 0.f, 0.f};
    for (int e = e0; e < e1; ++e) {
        const float al = alphal[e];
        const u16* wr = wv_bf + (size_t)psrc[e] * DWP;
#pragma unroll
        for (int j = 0; j < 5; ++j) acc[j] += al * bf2f(wr[lane + 64 * j]);
    }
#pragma unroll
    for (int j = 0; j < 5; ++j) {
        const int c = lane + 64 * j;
        if (c < DWR) zl[(size_t)node * DWR + c] = acc[j];
    }
}

__global__ __launch_bounds__(256) void addb_k(float* out, const float* __restrict__ b, int total)
{
    int id = blockIdx.x * 256 + threadIdx.x;
    if (id >= total) return;
    out[id] += b[id % NCLS];
}

__global__ __launch_bounds__(256) void diag_fill(float* out, int n, float v)
{
    int id = blockIdx.x * 256 + threadIdx.x;
    if (id < n) out[id] = v;
}

// ---------------- host ----------------
extern "C" void kernel_launch(void* const* d_in, const int* in_sizes, int n_in,
                              void* d_out, int out_size, void* d_ws, size_t ws_size,
                              hipStream_t stream)
{
    const float* n_f  = (const float*)d_in[0];
    const float* w2v  = (const float*)d_in[1];
    const float* s_f  = (const float*)d_in[2];
    const int*   src  = (const int*)d_in[3];
    const int*   dst  = (const int*)d_in[4];
    const float* W_e  = (const float*)d_in[5];
    const float* b_e  = (const float*)d_in[6];
    const float* W_el = (const float*)d_in[7];
    const float* b_el = (const float*)d_in[8];
    const float* W_a  = (const float*)d_in[9];
    const float* b_a  = (const float*)d_in[10];
    const float* W_al = (const float*)d_in[11];
    const float* b_al = (const float*)d_in[12];
    const float* W_n  = (const float*)d_in[13];
    const float* b_n  = (const float*)d_in[14];
    const float* W_nl = (const float*)d_in[15];
    const float* b_nl = (const float*)d_in[16];
    const float* W_r1 = (const float*)d_in[17];
    const float* b_r1 = (const float*)d_in[18];
    const float* W_r2 = (const float*)d_in[19];
    const float* b_r2 = (const float*)d_in[20];

    const int N = in_sizes[0] / ND;   // 20000
    const int E = in_sizes[3];        // 320000
    float* out = (float*)d_out;

    auto g1 = [](long long n) { return dim3((unsigned)((n + 255) / 256)); };

    char* base = (char*)d_ws;
    size_t off = 0;
    auto alloc = [&](size_t bytes) -> void* {
        void* r = base + off;
        off += (bytes + 255) & ~(size_t)255;
        return r;
    };
    u16* nf_bf = (u16*)alloc((size_t)N * ND * 2);
    u16* wv_bf = (u16*)alloc((size_t)N * DWP * 2);
    u16* sf_bf = (u16*)alloc((size_t)E * DSP * 2);
    u16* z_bf  = (u16*)alloc((size_t)N * ND * 2);
    u16* zl_bf = (u16*)alloc((size_t)N * DWP * 2);
    u16* WeT   = (u16*)alloc((size_t)512 * 1056 * 2);
    u16* WelT  = (u16*)alloc((size_t)512 * 640 * 2);
    u16* WnT   = (u16*)alloc((size_t)512 * 1024 * 2);
    u16* WnlT  = (u16*)alloc((size_t)384 * 640 * 2);
    u16* Wr1T  = (u16*)alloc((size_t)512 * 1696 * 2);
    float* aAs = (float*)alloc((size_t)E * 4);   // logits/alpha, sorted order
    float* aLs = (float*)alloc((size_t)E * 4);
    float* sD  = (float*)alloc((size_t)N * 4);
    float* sLd = (float*)alloc((size_t)N * 4);
    u32* mU    = (u32*)alloc((size_t)N * 4);
    u32* mL    = (u32*)alloc((size_t)N * 4);
    float* z   = (float*)alloc((size_t)N * ND * 4);
    float* zl  = (float*)alloc((size_t)N * DWR * 4);
    int* deg    = (int*)alloc((size_t)N * 4);
    int* offs   = (int*)alloc((size_t)N * 4);
    int* cursor = (int*)alloc((size_t)N * 4);
    int* perm   = (int*)alloc((size_t)E * 4);
    int* psrc   = (int*)alloc((size_t)E * 4);
    int* pdst   = (int*)alloc((size_t)E * 4);
    // lifetime aliasing: z/zl dead after cvt; reuse for node-MLP outputs.
    u16* nn_bf = (u16*)z;
    u16* wn_bf = (u16*)zl;

    if (off > ws_size) {
        diag_fill<<<g1(out_size), 256, 0, stream>>>(out, out_size, 2.0e6f);
        return;
    }

    hipMemsetAsync(z,   0, (size_t)N * ND * 4, stream);
    hipMemsetAsync(aAs, 0, (size_t)E * 4, stream);
    hipMemsetAsync(aLs, 0, (size_t)E * 4, stream);
    hipMemsetAsync(sD,  0, (size_t)N * 4, stream);
    hipMemsetAsync(sLd, 0, (size_t)N * 4, stream);
    hipMemsetAsync(mU,  0, (size_t)N * 4, stream);
    hipMemsetAsync(mL,  0, (size_t)N * 4, stream);
    hipMemsetAsync(deg, 0, (size_t)N * 4, stream);
    hipMemsetAsync(out, 0, (size_t)out_size * 4, stream);

    // sort edges by dst
    hist_k<<<g1(E), 256, 0, stream>>>(dst, deg, E);
    scan_k<<<dim3(1), 1024, 0, stream>>>(deg, offs, cursor, N);
    scat_perm_k<<<g1(E), 256, 0, stream>>>(src, dst, cursor, perm, psrc, pdst, E);

    cvt_bf<<<g1((long long)N * ND), 256, 0, stream>>>(n_f, nf_bf, N, ND, ND);
    cvt_bf<<<g1((long long)N * DWP), 256, 0, stream>>>(w2v, wv_bf, N, DWR, DWP);
    cvt_bf<<<g1((long long)E * DSP), 256, 0, stream>>>(s_f, sf_bf, E, DSR, DSP);

    { TSegs t{}; t.t[0] = {0,512,512}; t.t[1] = {528,512,512}; t.t[2] = {512,16,32};
      wtrans<<<g1(512 * 1056), 256, 0, stream>>>(W_e, 512, 512, 512, 1056, t, 3, WeT); }
    { TSegs t{}; t.t[0] = {0,300,320}; t.t[1] = {300,300,320};
      wtrans<<<g1(512 * 640), 256, 0, stream>>>(W_el, 512, 512, 512, 640, t, 2, WelT); }
    { TSegs t{}; t.t[0] = {0,512,512}; t.t[1] = {512,512,512};
      wtrans<<<g1(512 * 1024), 256, 0, stream>>>(W_n, 512, 512, 512, 1024, t, 2, WnT); }
    { TSegs t{}; t.t[0] = {0,300,320}; t.t[1] = {300,300,320};
      wtrans<<<g1(384 * 640), 256, 0, stream>>>(W_nl, 300, 300, 384, 640, t, 2, WnlT); }
    { TSegs t{}; t.t[0] = {0,512,512}; t.t[1] = {512,300,320}; t.t[2] = {812,16,32};
      t.t[3] = {828,300,320}; t.t[4] = {1128,512,512};
      wtrans<<<g1(512 * 1696), 256, 0, stream>>>(W_r1, 512, 512, 512, 1696, t, 5, Wr1T); }

    // edge MLP pass 1 (sorted rows): attention logits only
    { GSegs s{}; s.s[0] = {nf_bf, psrc, ND, 512}; s.s[1] = {nf_bf, pdst, ND, 512}; s.s[2] = {sf_bf, perm, DSP, 32};
      gemm_k<0,1,0><<<dim3(E / 128, 4), 256, 0, stream>>>(E, 512, s, WeT, 1056, b_e, 512,
          nullptr, 0, W_a, aAs, nullptr, nullptr, nullptr, 0); }
    // lang edge MLP (sorted rows): attention logits only
    { GSegs s{}; s.s[0] = {wv_bf, psrc, DWP, 320}; s.s[1] = {wv_bf, pdst, DWP, 320};
      gemm_k<0,1,0><<<dim3(E / 128, 4), 256, 0, stream>>>(E, 512, s, WelT, 640, b_el, 512,
          nullptr, 0, W_al, aLs, nullptr, nullptr, nullptr, 0); }

    att_fin<<<g1(E), 256, 0, stream>>>(aAs, aLs, b_a, b_al, E);
    segmax_k<<<g1(E), 256, 0, stream>>>(aAs, aLs, pdst, mU, mL, E);
    expsum_k<<<g1(E), 256, 0, stream>>>(aAs, aLs, pdst, mU, mL, sD, sLd, E);
    alpha_k<<<g1(E), 256, 0, stream>>>(aAs, aLs, pdst, sD, sLd, E);

    // edge MLP pass 2: recompute e_f, segment-reduce alpha*e_f into z
    { GSegs s{}; s.s[0] = {nf_bf, psrc, ND, 512}; s.s[1] = {nf_bf, pdst, ND, 512}; s.s[2] = {sf_bf, perm, DSP, 32};
      gemm_k<0,0,1><<<dim3(E / 128, 4), 256, 0, stream>>>(E, 512, s, WeT, 1056, b_e, 512,
          nullptr, 0, nullptr, nullptr, pdst, aAs, z, ND); }
    // z_l aggregation: per-node gather, no atomics
    agg_zl_seg<<<dim3((N + 3) / 4), 256, 0, stream>>>(wv_bf, aLs, psrc, offs, zl, N, E);

    cvt_bf<<<g1((long long)N * ND), 256, 0, stream>>>(z, z_bf, N, ND, ND);
    cvt_bf<<<g1((long long)N * DWP), 256, 0, stream>>>(zl, zl_bf, N, DWR, DWP);

    // node MLPs
    { GSegs s{}; s.s[0] = {nf_bf, nullptr, ND, 512}; s.s[1] = {z_bf, nullptr, ND, 512};
      gemm_k<1,0,0><<<dim3((N + 127) / 128, 4), 256, 0, stream>>>(N, 512, s, WnT, 1024, b_n, 512,
          nn_bf, 512, nullptr, nullptr, nullptr, nullptr, nullptr, 0); }
    { GSegs s{}; s.s[0] = {wv_bf, nullptr, DWP, 320}; s.s[1] = {zl_bf, nullptr, DWP, 320};
      gemm_k<1,0,0><<<dim3((N + 127) / 128, 3), 256, 0, stream>>>(N, 320, s, WnlT, 640, b_nl, 300,
          wn_bf, DWP, nullptr, nullptr, nullptr, nullptr, nullptr, 0); }

    // readout: full-row blocks, LDS p-accumulation, zero global atomics
    { GSegs s{}; s.s[0] = {nn_bf, psrc, ND, 512}; s.s[1] = {wn_bf, psrc, DWP, 320}; s.s[2] = {sf_bf, perm, DSP, 32};
      s.s[3] = {wn_bf, pdst, DWP, 320}; s.s[4] = {nn_bf, pdst, ND, 512};
      readout_k<<<dim3(E / 128), 256, 0, stream>>>(E, s, Wr1T, 1696, b_r1, W_r2, perm, out); }

    addb_k<<<g1((long long)E * NCLS), 256, 0, stream>>>(out, b_r2, E * NCLS);

    hipError_t e = hipGetLastError();
    if (e != hipSuccess) {
        diag_fill<<<g1(out_size), 256, 0, stream>>>(out, out_size, 1.0e6f + (float)(int)e);
    }
}

// Round 5
// 1905.023 us; speedup vs baseline: 2.5542x; 1.8036x over previous
//
#include <hip/hip_runtime.h>

typedef unsigned short u16;
typedef unsigned int u32;
typedef __bf16 bf16x8 __attribute__((ext_vector_type(8)));
typedef float f32x4 __attribute__((ext_vector_type(4)));

#define ND 512
#define DWR 300
#define DWP 320
#define NCLS 13

__device__ __forceinline__ float bf2f(u16 u) { return __uint_as_float(((u32)u) << 16); }
__device__ __forceinline__ u16 f2bf(float f) {
    u32 u = __float_as_uint(f);
    u32 r = (u + 0x7FFFu + ((u >> 16) & 1u)) >> 16;
    return (u16)r;
}
__device__ __forceinline__ u32 encf(float x) {
    int i = __float_as_int(x);
    return (i < 0) ? ~(u32)i : ((u32)i | 0x80000000u);
}
__device__ __forceinline__ float decf(u32 u) {
    int i = (u & 0x80000000u) ? (int)(u & 0x7FFFFFFFu) : (int)~u;
    return __int_as_float(i);
}
__device__ __forceinline__ void ld8f(const u16* p, float* v) {
    union { float4 f; u16 u[8]; } U;
    U.f = *(const float4*)p;
#pragma unroll
    for (int k = 0; k < 8; ++k) v[k] = bf2f(U.u[k]);
}

struct GSeg { const u16* base; const int* idx; int stride; int width; };
struct GSegs { GSeg s[5]; };
struct TSeg { int src_begin; int wreal; int wpad; };
struct TSegs { TSeg t[5]; };

// ---------------- node-domain gather-GEMM: C = [relu](A @ BT^T + bias), bf16 out ----------------
template<int RELU>
__global__ __launch_bounds__(256) void gemm_k(
    int M, int Nout, GSegs segs,
    const u16* __restrict__ BT, int ldb,
    const float* __restrict__ bias, int bias_n,
    u16* __restrict__ outb, int ldo)
{
    __shared__ __align__(16) u16 As[128 * 40];
    __shared__ __align__(16) u16 Bs[128 * 40];
    const int tid = threadIdx.x;

    // bijective XCD-friendly swizzle
    const int gx = gridDim.x, gy = gridDim.y;
    const int g0 = blockIdx.x + gx * blockIdx.y;
    int xt, yt;
    {
        const int fullg = gx >> 3;
        const int gsz = 8 * gy;
        if (g0 < fullg * gsz) {
            const int grp = g0 / gsz, w = g0 % gsz;
            xt = grp * 8 + (w & 7); yt = w >> 3;
        } else {
            const int remx = gx - fullg * 8;
            const int t = g0 - fullg * gsz;
            xt = fullg * 8 + t % remx; yt = t / remx;
        }
    }
    const int m0 = xt * 128, n0 = yt * 128;

    const int row = tid >> 1, half = tid & 1;
    int mrow = m0 + row; if (mrow >= M) mrow = M - 1;
    const int lane = tid & 63, wid = tid >> 6;
    const int wr = (wid >> 1) * 64, wc = (wid & 1) * 64;
    const int lr = lane & 15, lg = lane >> 4;

    f32x4 acc[4][4];
    for (int fm = 0; fm < 4; fm++)
        for (int fn = 0; fn < 4; fn++)
            acc[fm][fn] = f32x4{0.f, 0.f, 0.f, 0.f};

    const u16* brow = BT + (size_t)(n0 + row) * ldb + half * 16;

    auto do_step = [&](const u16* ga_, const u16* gb_) {
        float4 a0 = *(const float4*)ga_;
        float4 a1 = *(const float4*)(ga_ + 8);
        float4 b0 = *(const float4*)gb_;
        float4 b1 = *(const float4*)(gb_ + 8);
        __syncthreads();
        *(float4*)&As[row * 40 + half * 16]     = a0;
        *(float4*)&As[row * 40 + half * 16 + 8] = a1;
        *(float4*)&Bs[row * 40 + half * 16]     = b0;
        *(float4*)&Bs[row * 40 + half * 16 + 8] = b1;
        __syncthreads();
        bf16x8 af[4], bfv[4];
#pragma unroll
        for (int f = 0; f < 4; f++) {
            af[f]  = *(const bf16x8*)&As[(wr + f * 16 + lr) * 40 + lg * 8];
            bfv[f] = *(const bf16x8*)&Bs[(wc + f * 16 + lr) * 40 + lg * 8];
        }
#pragma unroll
        for (int fm = 0; fm < 4; fm++)
#pragma unroll
            for (int fn = 0; fn < 4; fn++)
                acc[fm][fn] = __builtin_amdgcn_mfma_f32_16x16x32_bf16(af[fm], bfv[fn], acc[fm][fn], 0, 0, 0);
    };

    int k0 = 0;
#pragma unroll
    for (int sI = 0; sI < 5; sI++) {
        const GSeg S = segs.s[sI];
        if (S.width > 0) {
            const int ridx = S.idx ? S.idx[mrow] : mrow;
            const u16* abase = S.base + (size_t)ridx * S.stride + half * 16;
            for (int kk = 0; kk < S.width; kk += 32) {
                do_step(abase + kk, brow + k0 + kk);
            }
            k0 += S.width;
        }
    }

#pragma unroll
    for (int fm = 0; fm < 4; fm++) {
#pragma unroll
        for (int i = 0; i < 4; i++) {
            const int grow = m0 + wr + fm * 16 + lg * 4 + i;
            const bool rok = grow < M;
#pragma unroll
            for (int fn = 0; fn < 4; fn++) {
                const int col = n0 + wc + fn * 16 + lr;
                float v = acc[fm][fn][i];
                v += (col < bias_n) ? bias[col] : 0.f;
                if (RELU) v = fmaxf(v, 0.f);
                if (rok && col < Nout) outb[(size_t)grow * ldo + col] = f2bf(v);
            }
        }
    }
}

// ---------------- per-edge pass 1: attention logits ----------------
__global__ __launch_bounds__(256) void pass1_k(
    const u16* __restrict__ Q, const u16* __restrict__ Lq,
    const float* __restrict__ s_f, const float* __restrict__ wmid,
    const int* __restrict__ psrc, const int* __restrict__ pdst, const int* __restrict__ perm,
    const float* __restrict__ W_a, const float* __restrict__ W_al,
    const float* __restrict__ b_e, const float* __restrict__ b_el,
    const float* __restrict__ b_a, const float* __restrict__ b_al,
    float* __restrict__ aA, float* __restrict__ aL, int E)
{
    __shared__ __align__(16) u16 wmids[16 * 512];
    const int tid = threadIdx.x;
    for (int i = tid; i < 16 * 512; i += 256) wmids[i] = f2bf(wmid[i]);
    __syncthreads();
    const int lane = tid & 63;
    const int col0 = lane * 8;
    float wa[8], wal[8], be[8], bel[8];
#pragma unroll
    for (int k = 0; k < 8; ++k) {
        wa[k] = W_a[col0 + k]; wal[k] = W_al[col0 + k];
        be[k] = b_e[col0 + k]; bel[k] = b_el[col0 + k];
    }
    const float ba = b_a[0], bal = b_al[0];
    const int nw = gridDim.x * 4;
    for (int e = blockIdx.x * 4 + (tid >> 6); e < E; e += nw) {
        const int ps = psrc[e], pd = pdst[e], pe = perm[e];
        const float4* sp = (const float4*)(s_f + (size_t)pe * 16);
        float4 s0 = sp[0], s1 = sp[1], s2 = sp[2], s3 = sp[3];
        float sfv[16] = {s0.x, s0.y, s0.z, s0.w, s1.x, s1.y, s1.z, s1.w,
                         s2.x, s2.y, s2.z, s2.w, s3.x, s3.y, s3.z, s3.w};
        float q1[8], q2[8], v[8];
        ld8f(Q + (size_t)ps * 1024 + col0, q1);
        ld8f(Q + (size_t)pd * 1024 + 512 + col0, q2);
#pragma unroll
        for (int k = 0; k < 8; ++k) v[k] = q1[k] + q2[k] + be[k];
#pragma unroll
        for (int j = 0; j < 16; ++j) {
            union { float4 f; u16 u[8]; } W;
            W.f = *(const float4*)&wmids[j * 512 + col0];
#pragma unroll
            for (int k = 0; k < 8; ++k) v[k] = fmaf(sfv[j], bf2f(W.u[k]), v[k]);
        }
        float ap = 0.f;
#pragma unroll
        for (int k = 0; k < 8; ++k) ap = fmaf(fmaxf(v[k], 0.f), wa[k], ap);
        float l1[8], l2[8];
        ld8f(Lq + (size_t)ps * 1024 + col0, l1);
        ld8f(Lq + (size_t)pd * 1024 + 512 + col0, l2);
        float alp = 0.f;
#pragma unroll
        for (int k = 0; k < 8; ++k) alp = fmaf(fmaxf(l1[k] + l2[k] + bel[k], 0.f), wal[k], alp);
#pragma unroll
        for (int off = 32; off >= 1; off >>= 1) {
            ap  += __shfl_xor(ap, off, 64);
            alp += __shfl_xor(alp, off, 64);
        }
        if (lane == 0) {
            float x = ap + ba;   aA[e] = x > 0.f ? x : 0.2f * x;
            float y = alp + bal; aL[e] = y > 0.f ? y : 0.2f * y;
        }
    }
}

// ---------------- per-node pass 2: z aggregation (direct bf16, no atomics) ----------------
__global__ __launch_bounds__(256) void pass2_k(
    const u16* __restrict__ Q, const float* __restrict__ s_f, const float* __restrict__ wmid,
    const int* __restrict__ psrc, const int* __restrict__ perm, const int* __restrict__ offs,
    const float* __restrict__ alpha, const float* __restrict__ b_e,
    u16* __restrict__ z_bf, int N, int E)
{
    __shared__ __align__(16) u16 wmids[16 * 512];
    const int tid = threadIdx.x;
    for (int i = tid; i < 16 * 512; i += 256) wmids[i] = f2bf(wmid[i]);
    __syncthreads();
    const int node = blockIdx.x * 4 + (tid >> 6);
    if (node >= N) return;
    const int lane = tid & 63;
    const int col0 = lane * 8;
    float q2[8], be[8], acc[8];
    ld8f(Q + (size_t)node * 1024 + 512 + col0, q2);
#pragma unroll
    for (int k = 0; k < 8; ++k) { be[k] = b_e[col0 + k]; acc[k] = 0.f; }
    const int e0 = offs[node];
    const int e1 = (node + 1 < N) ? offs[node + 1] : E;
    for (int e = e0; e < e1; ++e) {
        const float al = alpha[e];
        const int ps = psrc[e], pe = perm[e];
        const float4* sp = (const float4*)(s_f + (size_t)pe * 16);
        float4 s0 = sp[0], s1 = sp[1], s2 = sp[2], s3 = sp[3];
        float sfv[16] = {s0.x, s0.y, s0.z, s0.w, s1.x, s1.y, s1.z, s1.w,
                         s2.x, s2.y, s2.z, s2.w, s3.x, s3.y, s3.z, s3.w};
        float v[8], q1[8];
        ld8f(Q + (size_t)ps * 1024 + col0, q1);
#pragma unroll
        for (int k = 0; k < 8; ++k) v[k] = q1[k] + q2[k] + be[k];
#pragma unroll
        for (int j = 0; j < 16; ++j) {
            union { float4 f; u16 u[8]; } W;
            W.f = *(const float4*)&wmids[j * 512 + col0];
#pragma unroll
            for (int k = 0; k < 8; ++k) v[k] = fmaf(sfv[j], bf2f(W.u[k]), v[k]);
        }
#pragma unroll
        for (int k = 0; k < 8; ++k) acc[k] = fmaf(al, fmaxf(v[k], 0.f), acc[k]);
    }
    union { float4 f; u16 u[8]; } O;
#pragma unroll
    for (int k = 0; k < 8; ++k) O.u[k] = f2bf(acc[k]);
    *(float4*)(z_bf + (size_t)node * 512 + col0) = O.f;
}

// ---------------- per-edge pass 3: readout (includes b_r2, original order) ----------------
__global__ __launch_bounds__(256) void pass3_k(
    const u16* __restrict__ P, const float* __restrict__ s_f, const float* __restrict__ wmid2,
    const int* __restrict__ psrc, const int* __restrict__ pdst, const int* __restrict__ perm,
    const float* __restrict__ b_r1, const float* __restrict__ w2, const float* __restrict__ b_r2,
    float* __restrict__ out, int E)
{
    __shared__ __align__(16) u16 wmids[16 * 512];
    __shared__ __align__(16) u16 w2Ts[NCLS * 512];
    const int tid = threadIdx.x;
    for (int i = tid; i < 16 * 512; i += 256) wmids[i] = f2bf(wmid2[i]);
    for (int i = tid; i < NCLS * 512; i += 256) {
        const int c = i >> 9, col = i & 511;
        w2Ts[i] = f2bf(w2[col * NCLS + c]);
    }
    __syncthreads();
    const int lane = tid & 63;
    const int col0 = lane * 8;
    float br[8];
#pragma unroll
    for (int k = 0; k < 8; ++k) br[k] = b_r1[col0 + k];
    float br2[NCLS];
#pragma unroll
    for (int c = 0; c < NCLS; ++c) br2[c] = b_r2[c];
    const int nw = gridDim.x * 4;
    for (int e = blockIdx.x * 4 + (tid >> 6); e < E; e += nw) {
        const int ps = psrc[e], pd = pdst[e], pe = perm[e];
        const float4* sp = (const float4*)(s_f + (size_t)pe * 16);
        float4 s0 = sp[0], s1 = sp[1], s2 = sp[2], s3 = sp[3];
        float sfv[16] = {s0.x, s0.y, s0.z, s0.w, s1.x, s1.y, s1.z, s1.w,
                         s2.x, s2.y, s2.z, s2.w, s3.x, s3.y, s3.z, s3.w};
        float p1[8], p2[8], v[8];
        ld8f(P + (size_t)ps * 1024 + col0, p1);
        ld8f(P + (size_t)pd * 1024 + 512 + col0, p2);
#pragma unroll
        for (int k = 0; k < 8; ++k) v[k] = p1[k] + p2[k] + br[k];
#pragma unroll
        for (int j = 0; j < 16; ++j) {
            union { float4 f; u16 u[8]; } W;
            W.f = *(const float4*)&wmids[j * 512 + col0];
#pragma unroll
            for (int k = 0; k < 8; ++k) v[k] = fmaf(sfv[j], bf2f(W.u[k]), v[k]);
        }
#pragma unroll
        for (int k = 0; k < 8; ++k) v[k] = fmaxf(v[k], 0.f);
        float pc[NCLS];
#pragma unroll
        for (int c = 0; c < NCLS; ++c) {
            union { float4 f; u16 u[8]; } W;
            W.f = *(const float4*)&w2Ts[c * 512 + col0];
            float t = 0.f;
#pragma unroll
            for (int k = 0; k < 8; ++k) t = fmaf(v[k], bf2f(W.u[k]), t);
            pc[c] = t;
        }
#pragma unroll
        for (int off = 32; off >= 1; off >>= 1) {
#pragma unroll
            for (int c = 0; c < NCLS; ++c) pc[c] += __shfl_xor(pc[c], off, 64);
        }
        if (lane == 0) {
#pragma unroll
            for (int c = 0; c < NCLS; ++c) out[(size_t)pe * NCLS + c] = pc[c] + br2[c];
        }
    }
}

// ---------------- small kernels ----------------
__global__ __launch_bounds__(256) void cvt_bf(const float* __restrict__ src, u16* __restrict__ dst,
                                              int R, int Cs, int Cd)
{
    int id = blockIdx.x * 256 + threadIdx.x;
    if (id >= R * Cd) return;
    int r = id / Cd, c = id % Cd;
    float v = (c < Cs) ? src[(size_t)r * Cs + c] : 0.f;
    dst[id] = f2bf(v);
}

__global__ __launch_bounds__(256) void wtrans(const float* __restrict__ W, int Nw, int Nreal,
                                              int NrowsOut, int ldk, TSegs ts, int nseg,
                                              u16* __restrict__ WT)
{
    int id = blockIdx.x * 256 + threadIdx.x;
    if (id >= NrowsOut * ldk) return;
    int n = id / ldk, kp = id % ldk;
    float v = 0.f;
    if (n < Nreal) {
        int off = 0;
#pragma unroll
        for (int s = 0; s < 5; s++) {
            if (s < nseg) {
                int kl = kp - off;
                if (kl >= 0 && kl < ts.t[s].wpad) {
                    if (kl < ts.t[s].wreal) v = W[(size_t)(ts.t[s].src_begin + kl) * Nw + n];
                }
                off += ts.t[s].wpad;
            }
        }
    }
    WT[id] = f2bf(v);
}

__global__ __launch_bounds__(256) void hist_k(const int* __restrict__ dst, int* __restrict__ deg, int E)
{
    int id = blockIdx.x * 256 + threadIdx.x;
    if (id < E) atomicAdd(&deg[dst[id]], 1);
}

__global__ __launch_bounds__(1024) void scan_k(const int* __restrict__ deg,
                                               int* __restrict__ offs, int* __restrict__ cursor, int N)
{
    __shared__ int ps[1024];
    const int t = threadIdx.x;
    const int per = (N + 1023) >> 10;
    int s = 0;
    for (int j = 0; j < per; j++) { int idx = t * per + j; if (idx < N) s += deg[idx]; }
    ps[t] = s; __syncthreads();
    for (int o = 1; o < 1024; o <<= 1) {
        int v = (t >= o) ? ps[t - o] : 0; __syncthreads();
        ps[t] += v; __syncthreads();
    }
    int run = ps[t] - s;
    for (int j = 0; j < per; j++) {
        int idx = t * per + j;
        if (idx < N) { offs[idx] = run; cursor[idx] = run; run += deg[idx]; }
    }
}

__global__ __launch_bounds__(256) void scat_perm_k(const int* __restrict__ src, const int* __restrict__ dst,
                                                   int* __restrict__ cursor, int* __restrict__ perm,
                                                   int* __restrict__ psrc, int* __restrict__ pdst, int E)
{
    int id = blockIdx.x * 256 + threadIdx.x;
    if (id >= E) return;
    int d = dst[id];
    int pos = atomicAdd(&cursor[d], 1);
    perm[pos] = id; psrc[pos] = src[id]; pdst[pos] = d;
}

__global__ __launch_bounds__(256) void segmax_k(const float* a, const float* al, const int* seg,
                                                u32* mu, u32* ml, int E)
{
    int id = blockIdx.x * 256 + threadIdx.x;
    if (id >= E) return;
    int d = seg[id];
    atomicMax(&mu[d], encf(a[id]));
    atomicMax(&ml[d], encf(al[id]));
}

__global__ __launch_bounds__(256) void expsum_k(float* a, float* al, const int* seg,
                                                const u32* mu, const u32* ml,
                                                float* s, float* sl, int E)
{
    int id = blockIdx.x * 256 + threadIdx.x;
    if (id >= E) return;
    int d = seg[id];
    float v = expf(a[id] - decf(mu[d]));  a[id] = v;  atomicAdd(&s[d], v);
    float w = expf(al[id] - decf(ml[d])); al[id] = w; atomicAdd(&sl[d], w);
}

__global__ __launch_bounds__(256) void alpha_k(float* a, float* al, const int* seg,
                                               const float* s, const float* sl, int E)
{
    int id = blockIdx.x * 256 + threadIdx.x;
    if (id >= E) return;
    int d = seg[id];
    a[id]  = a[id]  / (s[d]  + 1e-9f);
    al[id] = al[id] / (sl[d] + 1e-9f);
}

__global__ __launch_bounds__(256) void agg_zl_seg(const u16* __restrict__ wv_bf,
                                                  const float* __restrict__ alphal,
                                                  const int* __restrict__ psrc,
                                                  const int* __restrict__ offs,
                                                  float* __restrict__ zl, int N, int E)
{
    const int node = blockIdx.x * 4 + (threadIdx.x >> 6);
    const int lane = threadIdx.x & 63;
    if (node >= N) return;
    const int e0 = offs[node];
    const int e1 = (node + 1 < N) ? offs[node + 1] : E;
    float acc[5] = {0.f, 0.f, 0.f, 0.f, 0.f};
    for (int e = e0; e < e1; ++e) {
        const float al = alphal[e];
        const u16* wr = wv_bf + (size_t)psrc[e] * DWP;
#pragma unroll
        for (int j = 0; j < 5; ++j) acc[j] += al * bf2f(wr[lane + 64 * j]);
    }
#pragma unroll
    for (int j = 0; j < 5; ++j) {
        const int c = lane + 64 * j;
        if (c < DWR) zl[(size_t)node * DWR + c] = acc[j];
    }
}

__global__ __launch_bounds__(256) void diag_fill(float* out, int n, float v)
{
    int id = blockIdx.x * 256 + threadIdx.x;
    if (id < n) out[id] = v;
}

// ---------------- host ----------------
extern "C" void kernel_launch(void* const* d_in, const int* in_sizes, int n_in,
                              void* d_out, int out_size, void* d_ws, size_t ws_size,
                              hipStream_t stream)
{
    const float* n_f  = (const float*)d_in[0];
    const float* w2v  = (const float*)d_in[1];
    const float* s_f  = (const float*)d_in[2];
    const int*   src  = (const int*)d_in[3];
    const int*   dst  = (const int*)d_in[4];
    const float* W_e  = (const float*)d_in[5];
    const float* b_e  = (const float*)d_in[6];
    const float* W_el = (const float*)d_in[7];
    const float* b_el = (const float*)d_in[8];
    const float* W_a  = (const float*)d_in[9];
    const float* b_a  = (const float*)d_in[10];
    const float* W_al = (const float*)d_in[11];
    const float* b_al = (const float*)d_in[12];
    const float* W_n  = (const float*)d_in[13];
    const float* b_n  = (const float*)d_in[14];
    const float* W_nl = (const float*)d_in[15];
    const float* b_nl = (const float*)d_in[16];
    const float* W_r1 = (const float*)d_in[17];
    const float* b_r1 = (const float*)d_in[18];
    const float* W_r2 = (const float*)d_in[19];
    const float* b_r2 = (const float*)d_in[20];

    const int N = in_sizes[0] / ND;   // 20000
    const int E = in_sizes[3];        // 320000
    float* out = (float*)d_out;

    auto g1 = [](long long n) { return dim3((unsigned)((n + 255) / 256)); };

    char* base = (char*)d_ws;
    size_t off = 0;
    auto alloc = [&](size_t bytes) -> void* {
        void* r = base + off;
        off += (bytes + 255) & ~(size_t)255;
        return r;
    };
    u16* nf_bf = (u16*)alloc((size_t)N * ND * 2);
    u16* wv_bf = (u16*)alloc((size_t)N * DWP * 2);
    u16* Q     = (u16*)alloc((size_t)N * 1024 * 2);
    u16* Lq    = (u16*)alloc((size_t)N * 1024 * 2);
    u16* Pt    = (u16*)alloc((size_t)N * 1024 * 2);
    u16* z_bf  = (u16*)alloc((size_t)N * ND * 2);
    u16* zl_bf = (u16*)alloc((size_t)N * DWP * 2);
    u16* nn_bf = (u16*)alloc((size_t)N * ND * 2);
    float* zl  = (float*)alloc((size_t)N * DWR * 4);
    u16* QT    = (u16*)alloc((size_t)1024 * 512 * 2);
    u16* LT    = (u16*)alloc((size_t)1024 * 320 * 2);
    u16* WnT   = (u16*)alloc((size_t)512 * 1024 * 2);
    u16* WnlT  = (u16*)alloc((size_t)384 * 640 * 2);
    u16* PrT   = (u16*)alloc((size_t)1024 * 832 * 2);
    float* aAs = (float*)alloc((size_t)E * 4);
    float* aLs = (float*)alloc((size_t)E * 4);
    float* sD  = (float*)alloc((size_t)N * 4);
    float* sLd = (float*)alloc((size_t)N * 4);
    u32* mU    = (u32*)alloc((size_t)N * 4);
    u32* mL    = (u32*)alloc((size_t)N * 4);
    int* deg    = (int*)alloc((size_t)N * 4);
    int* offs   = (int*)alloc((size_t)N * 4);
    int* cursor = (int*)alloc((size_t)N * 4);
    int* perm   = (int*)alloc((size_t)E * 4);
    int* psrc   = (int*)alloc((size_t)E * 4);
    int* pdst   = (int*)alloc((size_t)E * 4);
    // lifetime aliasing: zl (f32) dead after cvt -> reuse for wn_bf
    u16* wn_bf = (u16*)zl;

    if (off > ws_size) {
        diag_fill<<<g1(out_size), 256, 0, stream>>>(out, out_size, 2.0e6f);
        return;
    }

    hipMemsetAsync(sD,  0, (size_t)N * 4, stream);
    hipMemsetAsync(sLd, 0, (size_t)N * 4, stream);
    hipMemsetAsync(mU,  0, (size_t)N * 4, stream);
    hipMemsetAsync(mL,  0, (size_t)N * 4, stream);
    hipMemsetAsync(deg, 0, (size_t)N * 4, stream);

    // sort edges by dst
    hist_k<<<g1(E), 256, 0, stream>>>(dst, deg, E);
    scan_k<<<dim3(1), 1024, 0, stream>>>(deg, offs, cursor, N);
    scat_perm_k<<<g1(E), 256, 0, stream>>>(src, dst, cursor, perm, psrc, pdst, E);

    cvt_bf<<<g1((long long)N * ND), 256, 0, stream>>>(n_f, nf_bf, N, ND, ND);
    cvt_bf<<<g1((long long)N * DWP), 256, 0, stream>>>(w2v, wv_bf, N, DWR, DWP);

    // weight prep
    { TSegs t{}; t.t[0] = {0,512,512};
      wtrans<<<g1(512 * 512), 256, 0, stream>>>(W_e, 512, 512, 512, 512, t, 1, QT); }
    { TSegs t{}; t.t[0] = {528,512,512};
      wtrans<<<g1(512 * 512), 256, 0, stream>>>(W_e, 512, 512, 512, 512, t, 1, QT + 512 * 512); }
    { TSegs t{}; t.t[0] = {0,300,320};
      wtrans<<<g1(512 * 320), 256, 0, stream>>>(W_el, 512, 512, 512, 320, t, 1, LT); }
    { TSegs t{}; t.t[0] = {300,300,320};
      wtrans<<<g1(512 * 320), 256, 0, stream>>>(W_el, 512, 512, 512, 320, t, 1, LT + 512 * 320); }
    { TSegs t{}; t.t[0] = {0,512,512}; t.t[1] = {512,512,512};
      wtrans<<<g1(512 * 1024), 256, 0, stream>>>(W_n, 512, 512, 512, 1024, t, 2, WnT); }
    { TSegs t{}; t.t[0] = {0,300,320}; t.t[1] = {300,300,320};
      wtrans<<<g1(384 * 640), 256, 0, stream>>>(W_nl, 300, 300, 384, 640, t, 2, WnlT); }
    { TSegs t{}; t.t[0] = {0,512,512}; t.t[1] = {512,300,320};
      wtrans<<<g1(512 * 832), 256, 0, stream>>>(W_r1, 512, 512, 512, 832, t, 2, PrT); }
    { TSegs t{}; t.t[0] = {1128,512,512}; t.t[1] = {828,300,320};
      wtrans<<<g1(512 * 832), 256, 0, stream>>>(W_r1, 512, 512, 512, 832, t, 2, PrT + 512 * 832); }

    const int gmx = (N + 127) / 128;

    // node projections Q, L
    { GSegs s{}; s.s[0] = {nf_bf, nullptr, ND, 512};
      gemm_k<0><<<dim3(gmx, 8), 256, 0, stream>>>(N, 1024, s, QT, 512, nullptr, 0, Q, 1024); }
    { GSegs s{}; s.s[0] = {wv_bf, nullptr, DWP, 320};
      gemm_k<0><<<dim3(gmx, 8), 256, 0, stream>>>(N, 1024, s, LT, 320, nullptr, 0, Lq, 1024); }

    // attention logits
    pass1_k<<<dim3(2048), 256, 0, stream>>>(Q, Lq, s_f, W_e + 512 * 512, psrc, pdst, perm,
                                            W_a, W_al, b_e, b_el, b_a, b_al, aAs, aLs, E);
    segmax_k<<<g1(E), 256, 0, stream>>>(aAs, aLs, pdst, mU, mL, E);
    expsum_k<<<g1(E), 256, 0, stream>>>(aAs, aLs, pdst, mU, mL, sD, sLd, E);
    alpha_k<<<g1(E), 256, 0, stream>>>(aAs, aLs, pdst, sD, sLd, E);

    // aggregations
    pass2_k<<<dim3((N + 3) / 4), 256, 0, stream>>>(Q, s_f, W_e + 512 * 512, psrc, perm, offs,
                                                   aAs, b_e, z_bf, N, E);
    agg_zl_seg<<<dim3((N + 3) / 4), 256, 0, stream>>>(wv_bf, aLs, psrc, offs, zl, N, E);
    cvt_bf<<<g1((long long)N * DWP), 256, 0, stream>>>(zl, zl_bf, N, DWR, DWP);

    // node MLPs
    { GSegs s{}; s.s[0] = {nf_bf, nullptr, ND, 512}; s.s[1] = {z_bf, nullptr, ND, 512};
      gemm_k<1><<<dim3(gmx, 4), 256, 0, stream>>>(N, 512, s, WnT, 1024, b_n, 512, nn_bf, 512); }
    { GSegs s{}; s.s[0] = {wv_bf, nullptr, DWP, 320}; s.s[1] = {zl_bf, nullptr, DWP, 320};
      gemm_k<1><<<dim3(gmx, 3), 256, 0, stream>>>(N, 320, s, WnlT, 640, b_nl, 300, wn_bf, DWP); }

    // readout projection P
    { GSegs s{}; s.s[0] = {nn_bf, nullptr, ND, 512}; s.s[1] = {wn_bf, nullptr, DWP, 320};
      gemm_k<0><<<dim3(gmx, 8), 256, 0, stream>>>(N, 1024, s, PrT, 832, nullptr, 0, Pt, 1024); }

    // readout per-edge pass (includes b_r2, writes original order)
    pass3_k<<<dim3(2048), 256, 0, stream>>>(Pt, s_f, W_r1 + 812 * 512, psrc, pdst, perm,
                                            b_r1, W_r2, b_r2, out, E);

    hipError_t e = hipGetLastError();
    if (e != hipSuccess) {
        diag_fill<<<g1(out_size), 256, 0, stream>>>(out, out_size, 1.0e6f + (float)(int)e);
    }
}